// Round 1
// baseline (2572.549 us; speedup 1.0000x reference)
//
#include <hip/hip_runtime.h>
#include <hip/hip_bf16.h>
#include <math.h>

namespace {

constexpr int S   = 2048;
constexpr int D   = 1024;   // d_model
constexpr int H   = 16;     // heads
constexpr int DH  = 64;     // head dim
constexpr int B   = 2;      // batch
constexpr int M   = B * S;  // 4096 rows

// ---------------------------------------------------------------------------
// Fused QKV projection: x[4096][1024] @ {Wq,Wk,Wv}[1024][1024]
// Output layout: Q/K/V as [b*H + h][s][64] for attention-friendly reads.
// 64x64 tile, BK=16, 256 threads, 4x4 micro-tile per thread per matrix.
// ---------------------------------------------------------------------------
__global__ __launch_bounds__(256) void qkv_gemm(
    const float* __restrict__ x,  const float* __restrict__ Wq,
    const float* __restrict__ Wk, const float* __restrict__ Wv,
    float* __restrict__ Qo, float* __restrict__ Ko, float* __restrict__ Vo)
{
    __shared__ float As[16][68];   // x tile, [k][m], padded (272B rows: 16B-aligned, 2-way banks)
    __shared__ float Bq[16][64];
    __shared__ float Bk[16][64];
    __shared__ float Bv[16][64];

    const int tid = threadIdx.x;
    const int bn  = blockIdx.x;          // 0..15  (== head index, since BN == DH)
    const int bm  = blockIdx.y;          // 0..63
    const int m0  = bm * 64, n0 = bn * 64;
    const int tx  = tid & 15;            // micro-tile col group
    const int ty  = tid >> 4;            // micro-tile row group (0..15)
    const int lr  = tid >> 2;            // x-load row 0..63
    const int lk  = (tid & 3) * 4;       // x-load k offset

    float aq[4][4] = {}; float ak[4][4] = {}; float av[4][4] = {};

    for (int k0 = 0; k0 < D; k0 += 16) {
        float4 xv = *(const float4*)&x[(size_t)(m0 + lr) * D + k0 + lk];
        As[lk + 0][lr] = xv.x;
        As[lk + 1][lr] = xv.y;
        As[lk + 2][lr] = xv.z;
        As[lk + 3][lr] = xv.w;
        const size_t wo = (size_t)(k0 + ty) * D + n0 + tx * 4;
        *(float4*)&Bq[ty][tx * 4] = *(const float4*)&Wq[wo];
        *(float4*)&Bk[ty][tx * 4] = *(const float4*)&Wk[wo];
        *(float4*)&Bv[ty][tx * 4] = *(const float4*)&Wv[wo];
        __syncthreads();
        #pragma unroll
        for (int kk = 0; kk < 16; ++kk) {
            float4 a4  = *(const float4*)&As[kk][ty * 4];
            float4 q4  = *(const float4*)&Bq[kk][tx * 4];
            float4 k4  = *(const float4*)&Bk[kk][tx * 4];
            float4 v4  = *(const float4*)&Bv[kk][tx * 4];
            const float ar[4] = {a4.x, a4.y, a4.z, a4.w};
            const float qr[4] = {q4.x, q4.y, q4.z, q4.w};
            const float kr[4] = {k4.x, k4.y, k4.z, k4.w};
            const float vr[4] = {v4.x, v4.y, v4.z, v4.w};
            #pragma unroll
            for (int i = 0; i < 4; ++i) {
                #pragma unroll
                for (int j = 0; j < 4; ++j) {
                    aq[i][j] += ar[i] * qr[j];
                    ak[i][j] += ar[i] * kr[j];
                    av[i][j] += ar[i] * vr[j];
                }
            }
        }
        __syncthreads();
    }

    #pragma unroll
    for (int i = 0; i < 4; ++i) {
        const int m = m0 + ty * 4 + i;
        const int b = m >> 11;            // m / 2048
        const int s = m & (S - 1);
        const size_t off = ((size_t)(b * H + bn) * S + s) * DH + tx * 4;
        *(float4*)&Qo[off] = make_float4(aq[i][0], aq[i][1], aq[i][2], aq[i][3]);
        *(float4*)&Ko[off] = make_float4(ak[i][0], ak[i][1], ak[i][2], ak[i][3]);
        *(float4*)&Vo[off] = make_float4(av[i][0], av[i][1], av[i][2], av[i][3]);
    }
}

// ---------------------------------------------------------------------------
// Causal flash attention, fp32. One wave (64 threads) per block; each thread
// owns one query row (q + 64-elem accumulator in registers). K/V tiles of
// 32x64 staged in LDS; all LDS reads are wave-broadcast (conflict-free).
// Output ctx written as [b][s][h][dh] == row-major [4096][1024].
// ---------------------------------------------------------------------------
__global__ __launch_bounds__(64) void attn_kernel(
    const float* __restrict__ Q, const float* __restrict__ K,
    const float* __restrict__ V, float* __restrict__ ctx)
{
    __shared__ float Ks[32][64];
    __shared__ float Vs[32][64];

    const int t  = threadIdx.x;
    const int qt = blockIdx.x;     // 0..31  (q tile of 64 rows)
    const int bh = blockIdx.y;     // 0..31
    const int q0 = qt * 64;
    const int qr = q0 + t;         // this thread's query row

    const float* Qp = Q + ((size_t)bh * S + qr) * DH;
    float q[DH];
    #pragma unroll
    for (int i = 0; i < DH / 4; ++i)
        *(float4*)&q[i * 4] = *(const float4*)&Qp[i * 4];

    float acc[DH];
    #pragma unroll
    for (int i = 0; i < DH; ++i) acc[i] = 0.f;
    float mrun = -1e30f, lrun = 0.f;

    const int ntiles = 2 * (qt + 1);           // 32-wide kv tiles, causal bound
    for (int kt = 0; kt < ntiles; ++kt) {
        const int kv0 = kt * 32;
        const float* Kp = K + ((size_t)bh * S + kv0) * DH;
        const float* Vp = V + ((size_t)bh * S + kv0) * DH;
        #pragma unroll
        for (int i = 0; i < 8; ++i) {
            const int idx = t + i * 64;        // 0..511
            const int row = idx >> 4;
            const int c   = (idx & 15) * 4;
            *(float4*)&Ks[row][c] = *(const float4*)&Kp[(size_t)row * DH + c];
            *(float4*)&Vs[row][c] = *(const float4*)&Vp[(size_t)row * DH + c];
        }
        __syncthreads();

        float p[32];
        #pragma unroll
        for (int j = 0; j < 32; ++j) {
            float s = 0.f;
            #pragma unroll
            for (int kk = 0; kk < 16; ++kk) {
                float4 kv = *(const float4*)&Ks[j][kk * 4];
                s += q[kk * 4 + 0] * kv.x + q[kk * 4 + 1] * kv.y
                   + q[kk * 4 + 2] * kv.z + q[kk * 4 + 3] * kv.w;
            }
            s *= 0.125f;                       // 1/sqrt(64)
            if (kv0 + j > qr) s = -1e30f;      // causal mask
            p[j] = s;
        }

        float tmax = p[0];
        #pragma unroll
        for (int j = 1; j < 32; ++j) tmax = fmaxf(tmax, p[j]);
        const float newm = fmaxf(mrun, tmax);
        const float corr = __expf(mrun - newm);
        lrun *= corr;
        #pragma unroll
        for (int i = 0; i < DH; ++i) acc[i] *= corr;
        float ls = 0.f;
        #pragma unroll
        for (int j = 0; j < 32; ++j) { p[j] = __expf(p[j] - newm); ls += p[j]; }
        lrun += ls;

        #pragma unroll
        for (int j = 0; j < 32; ++j) {
            const float pj = p[j];
            #pragma unroll
            for (int dq = 0; dq < 16; ++dq) {
                float4 v = *(const float4*)&Vs[j][dq * 4];
                acc[dq * 4 + 0] += pj * v.x;
                acc[dq * 4 + 1] += pj * v.y;
                acc[dq * 4 + 2] += pj * v.z;
                acc[dq * 4 + 3] += pj * v.w;
            }
        }
        mrun = newm;
        __syncthreads();
    }

    const float inv = 1.f / lrun;
    const int b = bh >> 4, h = bh & (H - 1);
    float* op = ctx + ((size_t)(b * S + qr)) * D + h * DH;
    #pragma unroll
    for (int i = 0; i < DH / 4; ++i) {
        *(float4*)&op[i * 4] = make_float4(acc[i*4+0]*inv, acc[i*4+1]*inv,
                                           acc[i*4+2]*inv, acc[i*4+3]*inv);
    }
}

// ---------------------------------------------------------------------------
// Output projection: ctx[4096][1024] @ Wo[1024][1024] + bo -> out[4096][1024]
// ---------------------------------------------------------------------------
__global__ __launch_bounds__(256) void out_gemm(
    const float* __restrict__ ctx, const float* __restrict__ Wo,
    const float* __restrict__ bo,  float* __restrict__ out)
{
    __shared__ float As[16][68];
    __shared__ float Bs[16][64];

    const int tid = threadIdx.x;
    const int bn  = blockIdx.x;
    const int bm  = blockIdx.y;
    const int m0  = bm * 64, n0 = bn * 64;
    const int tx  = tid & 15;
    const int ty  = tid >> 4;
    const int lr  = tid >> 2;
    const int lk  = (tid & 3) * 4;

    float acc[4][4] = {};

    for (int k0 = 0; k0 < D; k0 += 16) {
        float4 xv = *(const float4*)&ctx[(size_t)(m0 + lr) * D + k0 + lk];
        As[lk + 0][lr] = xv.x;
        As[lk + 1][lr] = xv.y;
        As[lk + 2][lr] = xv.z;
        As[lk + 3][lr] = xv.w;
        *(float4*)&Bs[ty][tx * 4] = *(const float4*)&Wo[(size_t)(k0 + ty) * D + n0 + tx * 4];
        __syncthreads();
        #pragma unroll
        for (int kk = 0; kk < 16; ++kk) {
            float4 a4 = *(const float4*)&As[kk][ty * 4];
            float4 b4 = *(const float4*)&Bs[kk][tx * 4];
            const float ar[4] = {a4.x, a4.y, a4.z, a4.w};
            const float br[4] = {b4.x, b4.y, b4.z, b4.w};
            #pragma unroll
            for (int i = 0; i < 4; ++i)
                #pragma unroll
                for (int j = 0; j < 4; ++j)
                    acc[i][j] += ar[i] * br[j];
        }
        __syncthreads();
    }

    const float4 bias = *(const float4*)&bo[n0 + tx * 4];
    #pragma unroll
    for (int i = 0; i < 4; ++i) {
        const int m = m0 + ty * 4 + i;
        *(float4*)&out[(size_t)m * D + n0 + tx * 4] =
            make_float4(acc[i][0] + bias.x, acc[i][1] + bias.y,
                        acc[i][2] + bias.z, acc[i][3] + bias.w);
    }
}

} // namespace

extern "C" void kernel_launch(void* const* d_in, const int* in_sizes, int n_in,
                              void* d_out, int out_size, void* d_ws, size_t ws_size,
                              hipStream_t stream) {
    const float* x  = (const float*)d_in[0];
    const float* Wq = (const float*)d_in[1];
    const float* Wk = (const float*)d_in[2];
    const float* Wv = (const float*)d_in[3];
    const float* Wo = (const float*)d_in[4];
    const float* bo = (const float*)d_in[5];
    float* out = (float*)d_out;

    // Workspace layout (fp32): Q | K | V | ctx, each 4096*1024 = 16 MB.
    float* Q = (float*)d_ws;
    float* K = Q + (size_t)M * D;
    float* V = K + (size_t)M * D;
    float* C = V + (size_t)M * D;

    qkv_gemm<<<dim3(D / 64, M / 64), 256, 0, stream>>>(x, Wq, Wk, Wv, Q, K, V);
    attn_kernel<<<dim3(S / 64, B * H), 64, 0, stream>>>(Q, K, V, C);
    out_gemm<<<dim3(D / 64, M / 64), 256, 0, stream>>>(C, Wo, bo, out);
}

// Round 2
// 619.534 us; speedup vs baseline: 4.1524x; 4.1524x over previous
//
#include <hip/hip_runtime.h>
#include <math.h>

namespace {

constexpr int S   = 2048;
constexpr int D   = 1024;   // d_model
constexpr int H   = 16;     // heads
constexpr int DH  = 64;     // head dim
constexpr int B   = 2;      // batch
constexpr int M   = B * S;  // 4096 rows

typedef __attribute__((ext_vector_type(8))) short bf16x8;   // 8 bf16 = 4 VGPR
typedef __attribute__((ext_vector_type(4))) float f32x4;

__device__ __forceinline__ unsigned short f2bf(float f) {
    unsigned u = __builtin_bit_cast(unsigned, f);
    u += 0x7fffu + ((u >> 16) & 1u);          // round-to-nearest-even
    return (unsigned short)(u >> 16);
}

// ---------------------------------------------------------------------------
// Fused QKV projection (fp32 compute): x[4096][1024] @ {Wq,Wk,Wv}.
// Emits bf16: Qb,Kb as [bh][s][64] row-major; Vt as [bh][64][s] (V transposed)
// so attention PV B-fragments are contiguous 16B/lane loads.
// ---------------------------------------------------------------------------
__global__ __launch_bounds__(256) void qkv_gemm(
    const float* __restrict__ x,  const float* __restrict__ Wq,
    const float* __restrict__ Wk, const float* __restrict__ Wv,
    unsigned short* __restrict__ Qb, unsigned short* __restrict__ Kb,
    unsigned short* __restrict__ Vt)
{
    __shared__ float As[16][68];
    __shared__ float Bq[16][64];
    __shared__ float Bk[16][64];
    __shared__ float Bv[16][64];

    const int tid = threadIdx.x;
    const int bn  = blockIdx.x;          // 0..15  == head index (BN == DH)
    const int bm  = blockIdx.y;          // 0..63
    const int m0  = bm * 64, n0 = bn * 64;
    const int tx  = tid & 15;
    const int ty  = tid >> 4;
    const int lr  = tid >> 2;
    const int lk  = (tid & 3) * 4;

    float aq[4][4] = {}; float ak[4][4] = {}; float av[4][4] = {};

    for (int k0 = 0; k0 < D; k0 += 16) {
        float4 xv = *(const float4*)&x[(size_t)(m0 + lr) * D + k0 + lk];
        As[lk + 0][lr] = xv.x;
        As[lk + 1][lr] = xv.y;
        As[lk + 2][lr] = xv.z;
        As[lk + 3][lr] = xv.w;
        const size_t wo = (size_t)(k0 + ty) * D + n0 + tx * 4;
        *(float4*)&Bq[ty][tx * 4] = *(const float4*)&Wq[wo];
        *(float4*)&Bk[ty][tx * 4] = *(const float4*)&Wk[wo];
        *(float4*)&Bv[ty][tx * 4] = *(const float4*)&Wv[wo];
        __syncthreads();
        #pragma unroll
        for (int kk = 0; kk < 16; ++kk) {
            float4 a4  = *(const float4*)&As[kk][ty * 4];
            float4 q4  = *(const float4*)&Bq[kk][tx * 4];
            float4 k4  = *(const float4*)&Bk[kk][tx * 4];
            float4 v4  = *(const float4*)&Bv[kk][tx * 4];
            const float ar[4] = {a4.x, a4.y, a4.z, a4.w};
            const float qr[4] = {q4.x, q4.y, q4.z, q4.w};
            const float kr[4] = {k4.x, k4.y, k4.z, k4.w};
            const float vr[4] = {v4.x, v4.y, v4.z, v4.w};
            #pragma unroll
            for (int i = 0; i < 4; ++i) {
                #pragma unroll
                for (int j = 0; j < 4; ++j) {
                    aq[i][j] += ar[i] * qr[j];
                    ak[i][j] += ar[i] * kr[j];
                    av[i][j] += ar[i] * vr[j];
                }
            }
        }
        __syncthreads();
    }

    const int b  = m0 >> 11;                 // tile never straddles batch
    const int s0 = (m0 & (S - 1)) + ty * 4;
    const int bh = b * H + bn;
    #pragma unroll
    for (int i = 0; i < 4; ++i) {
        const size_t off = ((size_t)bh * S + s0 + i) * DH + tx * 4;
        ushort4 uq, uk;
        uq.x = f2bf(aq[i][0]); uq.y = f2bf(aq[i][1]); uq.z = f2bf(aq[i][2]); uq.w = f2bf(aq[i][3]);
        uk.x = f2bf(ak[i][0]); uk.y = f2bf(ak[i][1]); uk.z = f2bf(ak[i][2]); uk.w = f2bf(ak[i][3]);
        *(ushort4*)&Qb[off] = uq;
        *(ushort4*)&Kb[off] = uk;
    }
    #pragma unroll
    for (int j = 0; j < 4; ++j) {           // V transposed: [bh][d][s]
        ushort4 uv;
        uv.x = f2bf(av[0][j]); uv.y = f2bf(av[1][j]); uv.z = f2bf(av[2][j]); uv.w = f2bf(av[3][j]);
        *(ushort4*)&Vt[((size_t)bh * DH + tx * 4 + j) * S + s0] = uv;
    }
}

// ---------------------------------------------------------------------------
// Causal flash attention with bf16 MFMA (16x16x32), fp32 accumulation.
// 4 independent waves/block, each owns 32 q-rows. KV tiles of 32, no LDS
// (K/V are 256KB/bh -> L2-resident; fragments loaded straight from global).
// S^T = mfma(K, Q): C layout row=kv'=(l>>4)*4+r, col=q'=l&15 (m89-verified).
// PV: A=P fragment rebuilt via ds_bpermute; B=V^T contiguous loads.
// ---------------------------------------------------------------------------
__global__ __launch_bounds__(256) void attn_mfma(
    const unsigned short* __restrict__ Qb, const unsigned short* __restrict__ Kb,
    const unsigned short* __restrict__ Vt, float* __restrict__ ctx)
{
    const int tid = threadIdx.x;
    const int l   = tid & 63;
    const int w   = tid >> 6;            // wave 0..3
    const int qt  = blockIdx.x;          // 0..15
    const int bh  = blockIdx.y;          // 0..31
    const int q0  = qt * 128 + w * 32;   // this wave's 32 q-rows
    const int lr  = l & 15;
    const int g   = l >> 4;              // 0..3
    const bool hi = (l >= 32);

    const unsigned short* Qp = Qb + (size_t)bh * S * DH;
    const unsigned short* Kp = Kb + (size_t)bh * S * DH;
    const unsigned short* Vp = Vt + (size_t)bh * DH * S;

    // Q fragments (held whole kernel): lane reads Q[q0+qs*16+lr][kf*32+g*8 ..+7]
    bf16x8 qf[2][2];
    #pragma unroll
    for (int qs = 0; qs < 2; ++qs)
        #pragma unroll
        for (int kf = 0; kf < 2; ++kf)
            qf[qs][kf] = *(const bf16x8*)&Qp[(size_t)(q0 + qs * 16 + lr) * DH + kf * 32 + g * 8];

    f32x4 acc[2][4];                     // [qsub][dsub]: rows q'=g*4+r, col d'=lr
    #pragma unroll
    for (int qs = 0; qs < 2; ++qs)
        #pragma unroll
        for (int ds = 0; ds < 4; ++ds)
            acc[qs][ds] = (f32x4){0.f, 0.f, 0.f, 0.f};
    float mrun[2] = {-3e38f, -3e38f};
    float lrun[2] = {0.f, 0.f};

    const int ntiles = q0 / 32 + 1;      // causal bound for this wave
    for (int kt = 0; kt < ntiles; ++kt) {
        const int kv0 = kt * 32;

        bf16x8 kfr[2][2];                // K fragments: rows kv0+ks*16+lr
        #pragma unroll
        for (int ks = 0; ks < 2; ++ks)
            #pragma unroll
            for (int kf = 0; kf < 2; ++kf)
                kfr[ks][kf] = *(const bf16x8*)&Kp[(size_t)(kv0 + ks * 16 + lr) * DH + kf * 32 + g * 8];

        bf16x8 vfr[4];                   // V^T fragments: V^T[ds*16+lr][kv0+g*8..+7]
        #pragma unroll
        for (int ds = 0; ds < 4; ++ds)
            vfr[ds] = *(const bf16x8*)&Vp[(size_t)(ds * 16 + lr) * S + kv0 + g * 8];

        // S^T = K_tile . Q^T  -> st[ks][qs]: row kv'=g*4+r, col q'=lr
        f32x4 st[2][2];
        #pragma unroll
        for (int ks = 0; ks < 2; ++ks)
            #pragma unroll
            for (int qs = 0; qs < 2; ++qs) {
                f32x4 c = (f32x4){0.f, 0.f, 0.f, 0.f};
                c = __builtin_amdgcn_mfma_f32_16x16x32_bf16(kfr[ks][0], qf[qs][0], c, 0, 0, 0);
                c = __builtin_amdgcn_mfma_f32_16x16x32_bf16(kfr[ks][1], qf[qs][1], c, 0, 0, 0);
                st[ks][qs] = c;
            }

        #pragma unroll
        for (int qs = 0; qs < 2; ++qs) {
            const int qg = q0 + qs * 16 + lr;        // this lane's q column
            float sm[2][4];
            float mloc = -3e38f;
            #pragma unroll
            for (int ks = 0; ks < 2; ++ks)
                #pragma unroll
                for (int r = 0; r < 4; ++r) {
                    const int kvg = kv0 + ks * 16 + g * 4 + r;
                    float sv = st[ks][qs][r] * 0.125f;   // 1/sqrt(64)
                    if (kvg > qg) sv = -3e38f;           // causal mask
                    sm[ks][r] = sv;
                    mloc = fmaxf(mloc, sv);
                }
            mloc = fmaxf(mloc, __shfl_xor(mloc, 16));
            mloc = fmaxf(mloc, __shfl_xor(mloc, 32));
            const float newm = fmaxf(mrun[qs], mloc);
            const float corr = __expf(mrun[qs] - newm);
            float p[2][4];
            float lloc = 0.f;
            #pragma unroll
            for (int ks = 0; ks < 2; ++ks)
                #pragma unroll
                for (int r = 0; r < 4; ++r) {
                    p[ks][r] = __expf(sm[ks][r] - newm);
                    lloc += p[ks][r];
                }
            lloc += __shfl_xor(lloc, 16);
            lloc += __shfl_xor(lloc, 32);
            lrun[qs] = lrun[qs] * corr + lloc;
            mrun[qs] = newm;

            // rescale acc rows (row q'=g*4+r needs corr of lane q')
            float cr[4];
            #pragma unroll
            for (int r = 0; r < 4; ++r) cr[r] = __shfl(corr, g * 4 + r, 16);
            #pragma unroll
            for (int ds = 0; ds < 4; ++ds)
                #pragma unroll
                for (int r = 0; r < 4; ++r) acc[qs][ds][r] *= cr[r];

            // pack P to bf16x2 words: pk[ks][i] holds kv = ks*16 + g*4 + {2i,2i+1}
            unsigned pk[2][2];
            #pragma unroll
            for (int ks = 0; ks < 2; ++ks) {
                pk[ks][0] = (unsigned)f2bf(p[ks][0]) | ((unsigned)f2bf(p[ks][1]) << 16);
                pk[ks][1] = (unsigned)f2bf(p[ks][2]) | ((unsigned)f2bf(p[ks][3]) << 16);
            }

            // Redistribute to PV A-fragment: lane needs P[q'=lr][kv=g*8+j], j=0..7.
            // Sources: L1 = lr + 32*(g&1) (kv 8g..8g+3), L2 = L1+16 (kv 8g+4..8g+7);
            // register bank ks = g>>1 (lanes<32 want pk[0], lanes>=32 pk[1]).
            const int i1 = (lr + ((l >> 4 & 1) << 5)) * 4;
            const int i2 = i1 + 64;
            const unsigned a00 = (unsigned)__builtin_amdgcn_ds_bpermute(i1, (int)pk[0][0]);
            const unsigned a01 = (unsigned)__builtin_amdgcn_ds_bpermute(i1, (int)pk[1][0]);
            const unsigned a10 = (unsigned)__builtin_amdgcn_ds_bpermute(i1, (int)pk[0][1]);
            const unsigned a11 = (unsigned)__builtin_amdgcn_ds_bpermute(i1, (int)pk[1][1]);
            const unsigned a20 = (unsigned)__builtin_amdgcn_ds_bpermute(i2, (int)pk[0][0]);
            const unsigned a21 = (unsigned)__builtin_amdgcn_ds_bpermute(i2, (int)pk[1][0]);
            const unsigned a30 = (unsigned)__builtin_amdgcn_ds_bpermute(i2, (int)pk[0][1]);
            const unsigned a31 = (unsigned)__builtin_amdgcn_ds_bpermute(i2, (int)pk[1][1]);
            union { unsigned u[4]; bf16x8 v; } pa;
            pa.u[0] = hi ? a01 : a00;
            pa.u[1] = hi ? a11 : a10;
            pa.u[2] = hi ? a21 : a20;
            pa.u[3] = hi ? a31 : a30;

            #pragma unroll
            for (int ds = 0; ds < 4; ++ds)
                acc[qs][ds] = __builtin_amdgcn_mfma_f32_16x16x32_bf16(pa.v, vfr[ds], acc[qs][ds], 0, 0, 0);
        }
    }

    // epilogue: normalize and store ctx as [b][s][h*64+d] fp32
    const int bb = bh >> 4, hh = bh & (H - 1);
    #pragma unroll
    for (int qs = 0; qs < 2; ++qs) {
        const float inv = 1.f / lrun[qs];
        float ir[4];
        #pragma unroll
        for (int r = 0; r < 4; ++r) ir[r] = __shfl(inv, g * 4 + r, 16);
        #pragma unroll
        for (int ds = 0; ds < 4; ++ds)
            #pragma unroll
            for (int r = 0; r < 4; ++r) {
                const int qg = q0 + qs * 16 + g * 4 + r;
                ctx[(size_t)(bb * S + qg) * D + hh * DH + ds * 16 + lr] = acc[qs][ds][r] * ir[r];
            }
    }
}

// ---------------------------------------------------------------------------
// Output projection: ctx[4096][1024] @ Wo[1024][1024] + bo (fp32)
// ---------------------------------------------------------------------------
__global__ __launch_bounds__(256) void out_gemm(
    const float* __restrict__ ctx, const float* __restrict__ Wo,
    const float* __restrict__ bo,  float* __restrict__ out)
{
    __shared__ float As[16][68];
    __shared__ float Bs[16][64];

    const int tid = threadIdx.x;
    const int bn  = blockIdx.x;
    const int bm  = blockIdx.y;
    const int m0  = bm * 64, n0 = bn * 64;
    const int tx  = tid & 15;
    const int ty  = tid >> 4;
    const int lr  = tid >> 2;
    const int lk  = (tid & 3) * 4;

    float acc[4][4] = {};

    for (int k0 = 0; k0 < D; k0 += 16) {
        float4 xv = *(const float4*)&ctx[(size_t)(m0 + lr) * D + k0 + lk];
        As[lk + 0][lr] = xv.x;
        As[lk + 1][lr] = xv.y;
        As[lk + 2][lr] = xv.z;
        As[lk + 3][lr] = xv.w;
        *(float4*)&Bs[ty][tx * 4] = *(const float4*)&Wo[(size_t)(k0 + ty) * D + n0 + tx * 4];
        __syncthreads();
        #pragma unroll
        for (int kk = 0; kk < 16; ++kk) {
            float4 a4 = *(const float4*)&As[kk][ty * 4];
            float4 b4 = *(const float4*)&Bs[kk][tx * 4];
            const float ar[4] = {a4.x, a4.y, a4.z, a4.w};
            const float br[4] = {b4.x, b4.y, b4.z, b4.w};
            #pragma unroll
            for (int i = 0; i < 4; ++i)
                #pragma unroll
                for (int j = 0; j < 4; ++j)
                    acc[i][j] += ar[i] * br[j];
        }
        __syncthreads();
    }

    const float4 bias = *(const float4*)&bo[n0 + tx * 4];
    #pragma unroll
    for (int i = 0; i < 4; ++i) {
        const int m = m0 + ty * 4 + i;
        *(float4*)&out[(size_t)m * D + n0 + tx * 4] =
            make_float4(acc[i][0] + bias.x, acc[i][1] + bias.y,
                        acc[i][2] + bias.z, acc[i][3] + bias.w);
    }
}

} // namespace

extern "C" void kernel_launch(void* const* d_in, const int* in_sizes, int n_in,
                              void* d_out, int out_size, void* d_ws, size_t ws_size,
                              hipStream_t stream) {
    const float* x  = (const float*)d_in[0];
    const float* Wq = (const float*)d_in[1];
    const float* Wk = (const float*)d_in[2];
    const float* Wv = (const float*)d_in[3];
    const float* Wo = (const float*)d_in[4];
    const float* bo = (const float*)d_in[5];
    float* out = (float*)d_out;

    // ws: Qb | Kb (bf16 [bh][s][64]) | Vt (bf16 [bh][64][s]) | ctx (fp32) = 40MB
    unsigned short* Qb = (unsigned short*)d_ws;
    unsigned short* Kb = Qb + (size_t)M * D;
    unsigned short* Vt = Kb + (size_t)M * D;
    float*          C  = (float*)(Vt + (size_t)M * D);

    qkv_gemm<<<dim3(D / 64, M / 64), 256, 0, stream>>>(x, Wq, Wk, Wv, Qb, Kb, Vt);
    attn_mfma<<<dim3(S / 128, B * H), 256, 0, stream>>>(Qb, Kb, Vt, C);
    out_gemm<<<dim3(D / 64, M / 64), 256, 0, stream>>>(C, Wo, bo, out);
}

// Round 3
// 266.078 us; speedup vs baseline: 9.6684x; 2.3284x over previous
//
#include <hip/hip_runtime.h>
#include <math.h>

namespace {

constexpr int S   = 2048;
constexpr int D   = 1024;   // d_model (= K for all GEMMs)
constexpr int H   = 16;     // heads
constexpr int DH  = 64;     // head dim
constexpr int B   = 2;      // batch
constexpr int M   = B * S;  // 4096 rows

typedef __attribute__((ext_vector_type(8))) short bf16x8;   // 8 bf16 = 4 VGPR
typedef __attribute__((ext_vector_type(4))) float f32x4;

__device__ __forceinline__ unsigned short f2bf(float f) {
    unsigned u = __builtin_bit_cast(unsigned, f);
    u += 0x7fffu + ((u >> 16) & 1u);          // round-to-nearest-even
    return (unsigned short)(u >> 16);
}

// ---------------------------------------------------------------------------
// convert_x: x fp32 [4096][1024] -> bf16
// ---------------------------------------------------------------------------
__global__ __launch_bounds__(256) void convert_x(
    const float* __restrict__ x, unsigned short* __restrict__ xb)
{
    const int i = (blockIdx.x * 256 + threadIdx.x) * 8;
    float4 a = *(const float4*)&x[i];
    float4 b = *(const float4*)&x[i + 4];
    ushort4 lo, hi;
    lo.x = f2bf(a.x); lo.y = f2bf(a.y); lo.z = f2bf(a.z); lo.w = f2bf(a.w);
    hi.x = f2bf(b.x); hi.y = f2bf(b.y); hi.z = f2bf(b.z); hi.w = f2bf(b.w);
    *(ushort4*)&xb[i]     = lo;
    *(ushort4*)&xb[i + 4] = hi;
}

// ---------------------------------------------------------------------------
// convert_w: W fp32 [k][n] -> Wt bf16 [mat][n][k] (transposed, n-major)
// mats: 0=Wq 1=Wk 2=Wv 3=Wo. Reads coalesced along n; 16B writes along k.
// ---------------------------------------------------------------------------
__global__ __launch_bounds__(64) void convert_w(
    const float* __restrict__ Wq, const float* __restrict__ Wk,
    const float* __restrict__ Wv, const float* __restrict__ Wo,
    unsigned short* __restrict__ Wt)
{
    const int mat = blockIdx.z;
    const float* W = (mat == 0) ? Wq : (mat == 1) ? Wk : (mat == 2) ? Wv : Wo;
    const int n  = blockIdx.y * 64 + threadIdx.x;
    const int k0 = blockIdx.x * 8;
    ushort4 u0, u1;
    u0.x = f2bf(W[(size_t)(k0 + 0) * D + n]);
    u0.y = f2bf(W[(size_t)(k0 + 1) * D + n]);
    u0.z = f2bf(W[(size_t)(k0 + 2) * D + n]);
    u0.w = f2bf(W[(size_t)(k0 + 3) * D + n]);
    u1.x = f2bf(W[(size_t)(k0 + 4) * D + n]);
    u1.y = f2bf(W[(size_t)(k0 + 5) * D + n]);
    u1.z = f2bf(W[(size_t)(k0 + 6) * D + n]);
    u1.w = f2bf(W[(size_t)(k0 + 7) * D + n]);
    unsigned short* o = Wt + (size_t)mat * D * D + (size_t)n * D + k0;
    *(ushort4*)&o[0] = u0;
    *(ushort4*)&o[4] = u1;
}

// ---------------------------------------------------------------------------
// QKV GEMM, bf16 MFMA 16x16x32. 128x128 tile, BK=32, 4 waves (2x2).
// A = xb [4096][1024], B = Wt[mat] [n][k]. Both LDS tiles [128 rows][32 k]
// with XOR swizzle slot^=(row>>2)&3 (64B rows -> 2-way banks, free).
// Epilogue writes attention layouts: Qb/Kb [bh][s][64], Vt [bh][64][s], bf16.
// ---------------------------------------------------------------------------
__global__ __launch_bounds__(256) void gemm_qkv(
    const unsigned short* __restrict__ xb, const unsigned short* __restrict__ Wt,
    unsigned short* __restrict__ Qb, unsigned short* __restrict__ Kb,
    unsigned short* __restrict__ Vt)
{
    __shared__ unsigned short As[128 * 32];
    __shared__ unsigned short Bs[128 * 32];

    const int tid = threadIdx.x;
    const int l  = tid & 63;
    const int w  = tid >> 6;
    const int lr = l & 15;
    const int g  = l >> 4;
    const int wr = w >> 1, wc = w & 1;

    const int bm  = blockIdx.y;
    const int bnl = blockIdx.x;          // 0..23
    const int mat = bnl >> 3;            // 0..2
    const int n0  = (bnl & 7) * 128;
    const int m0  = bm * 128;
    const unsigned short* Bp = Wt + (size_t)mat * D * D;

    const int srow  = tid >> 2;          // staging row within 64-row part
    const int sslot = tid & 3;
    const int rslot = g ^ ((lr >> 2) & 3);   // swizzled read slot (per-lane const)

    f32x4 acc[4][4];
    #pragma unroll
    for (int i = 0; i < 4; ++i)
        #pragma unroll
        for (int j = 0; j < 4; ++j) acc[i][j] = (f32x4){0.f, 0.f, 0.f, 0.f};

    bf16x8 ra[2], rb[2];
    int gs[2];
    #pragma unroll
    for (int p = 0; p < 2; ++p) gs[p] = sslot ^ (((p * 64 + srow) >> 2) & 3);

    #pragma unroll
    for (int p = 0; p < 2; ++p) {
        const int row = p * 64 + srow;
        ra[p] = *(const bf16x8*)&xb[(size_t)(m0 + row) * D + gs[p] * 8];
        rb[p] = *(const bf16x8*)&Bp[(size_t)(n0 + row) * D + gs[p] * 8];
    }

    for (int k0 = 0; k0 < D; k0 += 32) {
        __syncthreads();
        #pragma unroll
        for (int p = 0; p < 2; ++p) {
            const int row = p * 64 + srow;
            *(bf16x8*)&As[row * 32 + sslot * 8] = ra[p];
            *(bf16x8*)&Bs[row * 32 + sslot * 8] = rb[p];
        }
        __syncthreads();
        if (k0 + 32 < D) {
            #pragma unroll
            for (int p = 0; p < 2; ++p) {
                const int row = p * 64 + srow;
                ra[p] = *(const bf16x8*)&xb[(size_t)(m0 + row) * D + k0 + 32 + gs[p] * 8];
                rb[p] = *(const bf16x8*)&Bp[(size_t)(n0 + row) * D + k0 + 32 + gs[p] * 8];
            }
        }
        bf16x8 af[4], bfr[4];
        #pragma unroll
        for (int i = 0; i < 4; ++i) {
            af[i]  = *(const bf16x8*)&As[(wr * 64 + i * 16 + lr) * 32 + rslot * 8];
            bfr[i] = *(const bf16x8*)&Bs[(wc * 64 + i * 16 + lr) * 32 + rslot * 8];
        }
        #pragma unroll
        for (int mi = 0; mi < 4; ++mi)
            #pragma unroll
            for (int ni = 0; ni < 4; ++ni)
                acc[mi][ni] = __builtin_amdgcn_mfma_f32_16x16x32_bf16(
                    af[mi], bfr[ni], acc[mi][ni], 0, 0, 0);
    }

    // C[m][n]: m = m0+wr*64+mi*16+g*4+r, n = n0+wc*64+ni*16+lr (within matrix)
    const int b      = m0 >> 11;
    const int s_base = (m0 & (S - 1)) + wr * 64;
    if (mat == 2) {
        #pragma unroll
        for (int ni = 0; ni < 4; ++ni) {
            const int n  = n0 + wc * 64 + ni * 16 + lr;
            const int bh = b * H + (n >> 6);
            unsigned short* vp = Vt + ((size_t)bh * DH + (n & 63)) * S;
            #pragma unroll
            for (int mi = 0; mi < 4; ++mi) {
                const int s0 = s_base + mi * 16 + g * 4;
                ushort4 u;
                u.x = f2bf(acc[mi][ni][0]); u.y = f2bf(acc[mi][ni][1]);
                u.z = f2bf(acc[mi][ni][2]); u.w = f2bf(acc[mi][ni][3]);
                *(ushort4*)&vp[s0] = u;
            }
        }
    } else {
        unsigned short* Op = (mat == 0) ? Qb : Kb;
        #pragma unroll
        for (int mi = 0; mi < 4; ++mi)
            #pragma unroll
            for (int r = 0; r < 4; ++r) {
                const int s = s_base + mi * 16 + g * 4 + r;
                #pragma unroll
                for (int ni = 0; ni < 4; ++ni) {
                    const int n  = n0 + wc * 64 + ni * 16 + lr;
                    const int bh = b * H + (n >> 6);
                    Op[((size_t)bh * S + s) * DH + (n & 63)] = f2bf(acc[mi][ni][r]);
                }
            }
    }
}

// ---------------------------------------------------------------------------
// Output GEMM, bf16 MFMA. 64x128 tile, BK=32, 4 waves (2x2, each 32x64).
// A = ctxb [4096][1024] bf16, B = Wot [n][k]. fp32 out + bias.
// ---------------------------------------------------------------------------
__global__ __launch_bounds__(256) void gemm_out(
    const unsigned short* __restrict__ ctxb, const unsigned short* __restrict__ Wot,
    const float* __restrict__ bo, float* __restrict__ out)
{
    __shared__ unsigned short As[64 * 32];
    __shared__ unsigned short Bs[128 * 32];

    const int tid = threadIdx.x;
    const int l  = tid & 63;
    const int w  = tid >> 6;
    const int lr = l & 15;
    const int g  = l >> 4;
    const int wr = w >> 1, wc = w & 1;

    const int m0 = blockIdx.y * 64;
    const int n0 = blockIdx.x * 128;

    const int srow  = tid >> 2;
    const int sslot = tid & 3;
    const int rslot = g ^ ((lr >> 2) & 3);

    f32x4 acc[2][4];
    #pragma unroll
    for (int i = 0; i < 2; ++i)
        #pragma unroll
        for (int j = 0; j < 4; ++j) acc[i][j] = (f32x4){0.f, 0.f, 0.f, 0.f};

    bf16x8 ra, rb[2];
    const int gsA = sslot ^ ((srow >> 2) & 3);
    int gsB[2];
    #pragma unroll
    for (int p = 0; p < 2; ++p) gsB[p] = sslot ^ (((p * 64 + srow) >> 2) & 3);

    ra = *(const bf16x8*)&ctxb[(size_t)(m0 + srow) * D + gsA * 8];
    #pragma unroll
    for (int p = 0; p < 2; ++p)
        rb[p] = *(const bf16x8*)&Wot[(size_t)(n0 + p * 64 + srow) * D + gsB[p] * 8];

    for (int k0 = 0; k0 < D; k0 += 32) {
        __syncthreads();
        *(bf16x8*)&As[srow * 32 + sslot * 8] = ra;
        #pragma unroll
        for (int p = 0; p < 2; ++p)
            *(bf16x8*)&Bs[(p * 64 + srow) * 32 + sslot * 8] = rb[p];
        __syncthreads();
        if (k0 + 32 < D) {
            ra = *(const bf16x8*)&ctxb[(size_t)(m0 + srow) * D + k0 + 32 + gsA * 8];
            #pragma unroll
            for (int p = 0; p < 2; ++p)
                rb[p] = *(const bf16x8*)&Wot[(size_t)(n0 + p * 64 + srow) * D + k0 + 32 + gsB[p] * 8];
        }
        bf16x8 af[2], bfr[4];
        #pragma unroll
        for (int i = 0; i < 2; ++i)
            af[i] = *(const bf16x8*)&As[(wr * 32 + i * 16 + lr) * 32 + rslot * 8];
        #pragma unroll
        for (int i = 0; i < 4; ++i)
            bfr[i] = *(const bf16x8*)&Bs[(wc * 64 + i * 16 + lr) * 32 + rslot * 8];
        #pragma unroll
        for (int mi = 0; mi < 2; ++mi)
            #pragma unroll
            for (int ni = 0; ni < 4; ++ni)
                acc[mi][ni] = __builtin_amdgcn_mfma_f32_16x16x32_bf16(
                    af[mi], bfr[ni], acc[mi][ni], 0, 0, 0);
    }

    #pragma unroll
    for (int mi = 0; mi < 2; ++mi)
        #pragma unroll
        for (int ni = 0; ni < 4; ++ni) {
            const int n = n0 + wc * 64 + ni * 16 + lr;
            const float bias = bo[n];
            #pragma unroll
            for (int r = 0; r < 4; ++r) {
                const int m = m0 + wr * 32 + mi * 16 + g * 4 + r;
                out[(size_t)m * D + n] = acc[mi][ni][r] + bias;
            }
        }
}

// ---------------------------------------------------------------------------
// Causal flash attention with bf16 MFMA (16x16x32), fp32 accumulation.
// (unchanged from round 2 except ctx is now written as bf16)
// ---------------------------------------------------------------------------
__global__ __launch_bounds__(256) void attn_mfma(
    const unsigned short* __restrict__ Qb, const unsigned short* __restrict__ Kb,
    const unsigned short* __restrict__ Vt, unsigned short* __restrict__ ctxb)
{
    const int tid = threadIdx.x;
    const int l   = tid & 63;
    const int w   = tid >> 6;
    const int qt  = blockIdx.x;
    const int bh  = blockIdx.y;
    const int q0  = qt * 128 + w * 32;
    const int lr  = l & 15;
    const int g   = l >> 4;
    const bool hi = (l >= 32);

    const unsigned short* Qp = Qb + (size_t)bh * S * DH;
    const unsigned short* Kp = Kb + (size_t)bh * S * DH;
    const unsigned short* Vp = Vt + (size_t)bh * DH * S;

    bf16x8 qf[2][2];
    #pragma unroll
    for (int qs = 0; qs < 2; ++qs)
        #pragma unroll
        for (int kf = 0; kf < 2; ++kf)
            qf[qs][kf] = *(const bf16x8*)&Qp[(size_t)(q0 + qs * 16 + lr) * DH + kf * 32 + g * 8];

    f32x4 acc[2][4];
    #pragma unroll
    for (int qs = 0; qs < 2; ++qs)
        #pragma unroll
        for (int ds = 0; ds < 4; ++ds)
            acc[qs][ds] = (f32x4){0.f, 0.f, 0.f, 0.f};
    float mrun[2] = {-3e38f, -3e38f};
    float lrun[2] = {0.f, 0.f};

    const int ntiles = q0 / 32 + 1;
    for (int kt = 0; kt < ntiles; ++kt) {
        const int kv0 = kt * 32;

        bf16x8 kfr[2][2];
        #pragma unroll
        for (int ks = 0; ks < 2; ++ks)
            #pragma unroll
            for (int kf = 0; kf < 2; ++kf)
                kfr[ks][kf] = *(const bf16x8*)&Kp[(size_t)(kv0 + ks * 16 + lr) * DH + kf * 32 + g * 8];

        bf16x8 vfr[4];
        #pragma unroll
        for (int ds = 0; ds < 4; ++ds)
            vfr[ds] = *(const bf16x8*)&Vp[(size_t)(ds * 16 + lr) * S + kv0 + g * 8];

        f32x4 st[2][2];
        #pragma unroll
        for (int ks = 0; ks < 2; ++ks)
            #pragma unroll
            for (int qs = 0; qs < 2; ++qs) {
                f32x4 c = (f32x4){0.f, 0.f, 0.f, 0.f};
                c = __builtin_amdgcn_mfma_f32_16x16x32_bf16(kfr[ks][0], qf[qs][0], c, 0, 0, 0);
                c = __builtin_amdgcn_mfma_f32_16x16x32_bf16(kfr[ks][1], qf[qs][1], c, 0, 0, 0);
                st[ks][qs] = c;
            }

        #pragma unroll
        for (int qs = 0; qs < 2; ++qs) {
            const int qg = q0 + qs * 16 + lr;
            float sm[2][4];
            float mloc = -3e38f;
            #pragma unroll
            for (int ks = 0; ks < 2; ++ks)
                #pragma unroll
                for (int r = 0; r < 4; ++r) {
                    const int kvg = kv0 + ks * 16 + g * 4 + r;
                    float sv = st[ks][qs][r] * 0.125f;
                    if (kvg > qg) sv = -3e38f;
                    sm[ks][r] = sv;
                    mloc = fmaxf(mloc, sv);
                }
            mloc = fmaxf(mloc, __shfl_xor(mloc, 16));
            mloc = fmaxf(mloc, __shfl_xor(mloc, 32));
            const float newm = fmaxf(mrun[qs], mloc);
            const float corr = __expf(mrun[qs] - newm);
            float p[2][4];
            float lloc = 0.f;
            #pragma unroll
            for (int ks = 0; ks < 2; ++ks)
                #pragma unroll
                for (int r = 0; r < 4; ++r) {
                    p[ks][r] = __expf(sm[ks][r] - newm);
                    lloc += p[ks][r];
                }
            lloc += __shfl_xor(lloc, 16);
            lloc += __shfl_xor(lloc, 32);
            lrun[qs] = lrun[qs] * corr + lloc;
            mrun[qs] = newm;

            float cr[4];
            #pragma unroll
            for (int r = 0; r < 4; ++r) cr[r] = __shfl(corr, g * 4 + r, 16);
            #pragma unroll
            for (int ds = 0; ds < 4; ++ds)
                #pragma unroll
                for (int r = 0; r < 4; ++r) acc[qs][ds][r] *= cr[r];

            unsigned pk[2][2];
            #pragma unroll
            for (int ks = 0; ks < 2; ++ks) {
                pk[ks][0] = (unsigned)f2bf(p[ks][0]) | ((unsigned)f2bf(p[ks][1]) << 16);
                pk[ks][1] = (unsigned)f2bf(p[ks][2]) | ((unsigned)f2bf(p[ks][3]) << 16);
            }

            const int i1 = (lr + ((l >> 4 & 1) << 5)) * 4;
            const int i2 = i1 + 64;
            const unsigned a00 = (unsigned)__builtin_amdgcn_ds_bpermute(i1, (int)pk[0][0]);
            const unsigned a01 = (unsigned)__builtin_amdgcn_ds_bpermute(i1, (int)pk[1][0]);
            const unsigned a10 = (unsigned)__builtin_amdgcn_ds_bpermute(i1, (int)pk[0][1]);
            const unsigned a11 = (unsigned)__builtin_amdgcn_ds_bpermute(i1, (int)pk[1][1]);
            const unsigned a20 = (unsigned)__builtin_amdgcn_ds_bpermute(i2, (int)pk[0][0]);
            const unsigned a21 = (unsigned)__builtin_amdgcn_ds_bpermute(i2, (int)pk[1][0]);
            const unsigned a30 = (unsigned)__builtin_amdgcn_ds_bpermute(i2, (int)pk[0][1]);
            const unsigned a31 = (unsigned)__builtin_amdgcn_ds_bpermute(i2, (int)pk[1][1]);
            union { unsigned u[4]; bf16x8 v; } pa;
            pa.u[0] = hi ? a01 : a00;
            pa.u[1] = hi ? a11 : a10;
            pa.u[2] = hi ? a21 : a20;
            pa.u[3] = hi ? a31 : a30;

            #pragma unroll
            for (int ds = 0; ds < 4; ++ds)
                acc[qs][ds] = __builtin_amdgcn_mfma_f32_16x16x32_bf16(pa.v, vfr[ds], acc[qs][ds], 0, 0, 0);
        }
    }

    const int bb = bh >> 4, hh = bh & (H - 1);
    #pragma unroll
    for (int qs = 0; qs < 2; ++qs) {
        const float inv = 1.f / lrun[qs];
        float ir[4];
        #pragma unroll
        for (int r = 0; r < 4; ++r) ir[r] = __shfl(inv, g * 4 + r, 16);
        #pragma unroll
        for (int ds = 0; ds < 4; ++ds)
            #pragma unroll
            for (int r = 0; r < 4; ++r) {
                const int qg = q0 + qs * 16 + g * 4 + r;
                ctxb[(size_t)(bb * S + qg) * D + hh * DH + ds * 16 + lr] =
                    f2bf(acc[qs][ds][r] * ir[r]);
            }
    }
}

} // namespace

extern "C" void kernel_launch(void* const* d_in, const int* in_sizes, int n_in,
                              void* d_out, int out_size, void* d_ws, size_t ws_size,
                              hipStream_t stream) {
    const float* x  = (const float*)d_in[0];
    const float* Wq = (const float*)d_in[1];
    const float* Wk = (const float*)d_in[2];
    const float* Wv = (const float*)d_in[3];
    const float* Wo = (const float*)d_in[4];
    const float* bo = (const float*)d_in[5];
    float* out = (float*)d_out;

    // ws (bf16): xb 8MB | Wt 4x2MB | Qb 8MB | Kb 8MB | Vt 8MB | ctxb 8MB = 48MB
    unsigned short* xb   = (unsigned short*)d_ws;
    unsigned short* Wt   = xb + (size_t)M * D;
    unsigned short* Qb   = Wt + (size_t)4 * D * D;
    unsigned short* Kb   = Qb + (size_t)M * D;
    unsigned short* Vtp  = Kb + (size_t)M * D;
    unsigned short* ctxb = Vtp + (size_t)M * D;

    convert_x<<<dim3((M * D) / (256 * 8)), 256, 0, stream>>>(x, xb);
    convert_w<<<dim3(D / 8, D / 64, 4), 64, 0, stream>>>(Wq, Wk, Wv, Wo, Wt);
    gemm_qkv<<<dim3(24, M / 128), 256, 0, stream>>>(xb, Wt, Qb, Kb, Vtp);
    attn_mfma<<<dim3(S / 128, B * H), 256, 0, stream>>>(Qb, Kb, Vtp, ctxb);
    gemm_out<<<dim3(D / 128, M / 64), 256, 0, stream>>>(
        ctxb, Wt + (size_t)3 * D * D, bo, out);
}

// Round 4
// 265.593 us; speedup vs baseline: 9.6861x; 1.0018x over previous
//
#include <hip/hip_runtime.h>
#include <math.h>

namespace {

constexpr int S   = 2048;
constexpr int D   = 1024;   // d_model (= K for all GEMMs)
constexpr int H   = 16;     // heads
constexpr int DH  = 64;     // head dim
constexpr int B   = 2;      // batch
constexpr int M   = B * S;  // 4096 rows

typedef __attribute__((ext_vector_type(8)))  short bf16x8;   // 8 bf16 = 4 VGPR
typedef __attribute__((ext_vector_type(4)))  float f32x4;
typedef __attribute__((ext_vector_type(16))) float f32x16;

__device__ __forceinline__ unsigned short f2bf(float f) {
    unsigned u = __builtin_bit_cast(unsigned, f);
    u += 0x7fffu + ((u >> 16) & 1u);          // round-to-nearest-even
    return (unsigned short)(u >> 16);
}

__device__ __forceinline__ unsigned cvt_pk_bf16(float lo, float hi) {
    unsigned r;
    asm("v_cvt_pk_bf16_f32 %0, %1, %2" : "=v"(r) : "v"(lo), "v"(hi));
    return r;
}

// ---------------------------------------------------------------------------
// convert_x: x fp32 [4096][1024] -> bf16
// ---------------------------------------------------------------------------
__global__ __launch_bounds__(256) void convert_x(
    const float* __restrict__ x, unsigned short* __restrict__ xb)
{
    const int i = (blockIdx.x * 256 + threadIdx.x) * 8;
    float4 a = *(const float4*)&x[i];
    float4 b = *(const float4*)&x[i + 4];
    ushort4 lo, hi;
    lo.x = f2bf(a.x); lo.y = f2bf(a.y); lo.z = f2bf(a.z); lo.w = f2bf(a.w);
    hi.x = f2bf(b.x); hi.y = f2bf(b.y); hi.z = f2bf(b.z); hi.w = f2bf(b.w);
    *(ushort4*)&xb[i]     = lo;
    *(ushort4*)&xb[i + 4] = hi;
}

// ---------------------------------------------------------------------------
// convert_w: W fp32 [k][n] -> Wt bf16 [mat][n][k] (transposed, n-major)
// ---------------------------------------------------------------------------
__global__ __launch_bounds__(64) void convert_w(
    const float* __restrict__ Wq, const float* __restrict__ Wk,
    const float* __restrict__ Wv, const float* __restrict__ Wo,
    unsigned short* __restrict__ Wt)
{
    const int mat = blockIdx.z;
    const float* W = (mat == 0) ? Wq : (mat == 1) ? Wk : (mat == 2) ? Wv : Wo;
    const int n  = blockIdx.y * 64 + threadIdx.x;
    const int k0 = blockIdx.x * 8;
    ushort4 u0, u1;
    u0.x = f2bf(W[(size_t)(k0 + 0) * D + n]);
    u0.y = f2bf(W[(size_t)(k0 + 1) * D + n]);
    u0.z = f2bf(W[(size_t)(k0 + 2) * D + n]);
    u0.w = f2bf(W[(size_t)(k0 + 3) * D + n]);
    u1.x = f2bf(W[(size_t)(k0 + 4) * D + n]);
    u1.y = f2bf(W[(size_t)(k0 + 5) * D + n]);
    u1.z = f2bf(W[(size_t)(k0 + 6) * D + n]);
    u1.w = f2bf(W[(size_t)(k0 + 7) * D + n]);
    unsigned short* o = Wt + (size_t)mat * D * D + (size_t)n * D + k0;
    *(ushort4*)&o[0] = u0;
    *(ushort4*)&o[4] = u1;
}

// ---------------------------------------------------------------------------
// QKV GEMM, bf16 MFMA 16x16x32 (unchanged from round 3).
// ---------------------------------------------------------------------------
__global__ __launch_bounds__(256) void gemm_qkv(
    const unsigned short* __restrict__ xb, const unsigned short* __restrict__ Wt,
    unsigned short* __restrict__ Qb, unsigned short* __restrict__ Kb,
    unsigned short* __restrict__ Vt)
{
    __shared__ unsigned short As[128 * 32];
    __shared__ unsigned short Bs[128 * 32];

    const int tid = threadIdx.x;
    const int l  = tid & 63;
    const int w  = tid >> 6;
    const int lr = l & 15;
    const int g  = l >> 4;
    const int wr = w >> 1, wc = w & 1;

    const int bm  = blockIdx.y;
    const int bnl = blockIdx.x;          // 0..23
    const int mat = bnl >> 3;            // 0..2
    const int n0  = (bnl & 7) * 128;
    const int m0  = bm * 128;
    const unsigned short* Bp = Wt + (size_t)mat * D * D;

    const int srow  = tid >> 2;
    const int sslot = tid & 3;
    const int rslot = g ^ ((lr >> 2) & 3);

    f32x4 acc[4][4];
    #pragma unroll
    for (int i = 0; i < 4; ++i)
        #pragma unroll
        for (int j = 0; j < 4; ++j) acc[i][j] = (f32x4){0.f, 0.f, 0.f, 0.f};

    bf16x8 ra[2], rb[2];
    int gs[2];
    #pragma unroll
    for (int p = 0; p < 2; ++p) gs[p] = sslot ^ (((p * 64 + srow) >> 2) & 3);

    #pragma unroll
    for (int p = 0; p < 2; ++p) {
        const int row = p * 64 + srow;
        ra[p] = *(const bf16x8*)&xb[(size_t)(m0 + row) * D + gs[p] * 8];
        rb[p] = *(const bf16x8*)&Bp[(size_t)(n0 + row) * D + gs[p] * 8];
    }

    for (int k0 = 0; k0 < D; k0 += 32) {
        __syncthreads();
        #pragma unroll
        for (int p = 0; p < 2; ++p) {
            const int row = p * 64 + srow;
            *(bf16x8*)&As[row * 32 + sslot * 8] = ra[p];
            *(bf16x8*)&Bs[row * 32 + sslot * 8] = rb[p];
        }
        __syncthreads();
        if (k0 + 32 < D) {
            #pragma unroll
            for (int p = 0; p < 2; ++p) {
                const int row = p * 64 + srow;
                ra[p] = *(const bf16x8*)&xb[(size_t)(m0 + row) * D + k0 + 32 + gs[p] * 8];
                rb[p] = *(const bf16x8*)&Bp[(size_t)(n0 + row) * D + k0 + 32 + gs[p] * 8];
            }
        }
        bf16x8 af[4], bfr[4];
        #pragma unroll
        for (int i = 0; i < 4; ++i) {
            af[i]  = *(const bf16x8*)&As[(wr * 64 + i * 16 + lr) * 32 + rslot * 8];
            bfr[i] = *(const bf16x8*)&Bs[(wc * 64 + i * 16 + lr) * 32 + rslot * 8];
        }
        #pragma unroll
        for (int mi = 0; mi < 4; ++mi)
            #pragma unroll
            for (int ni = 0; ni < 4; ++ni)
                acc[mi][ni] = __builtin_amdgcn_mfma_f32_16x16x32_bf16(
                    af[mi], bfr[ni], acc[mi][ni], 0, 0, 0);
    }

    const int b      = m0 >> 11;
    const int s_base = (m0 & (S - 1)) + wr * 64;
    if (mat == 2) {
        #pragma unroll
        for (int ni = 0; ni < 4; ++ni) {
            const int n  = n0 + wc * 64 + ni * 16 + lr;
            const int bh = b * H + (n >> 6);
            unsigned short* vp = Vt + ((size_t)bh * DH + (n & 63)) * S;
            #pragma unroll
            for (int mi = 0; mi < 4; ++mi) {
                const int s0 = s_base + mi * 16 + g * 4;
                ushort4 u;
                u.x = f2bf(acc[mi][ni][0]); u.y = f2bf(acc[mi][ni][1]);
                u.z = f2bf(acc[mi][ni][2]); u.w = f2bf(acc[mi][ni][3]);
                *(ushort4*)&vp[s0] = u;
            }
        }
    } else {
        unsigned short* Op = (mat == 0) ? Qb : Kb;
        #pragma unroll
        for (int mi = 0; mi < 4; ++mi)
            #pragma unroll
            for (int r = 0; r < 4; ++r) {
                const int s = s_base + mi * 16 + g * 4 + r;
                #pragma unroll
                for (int ni = 0; ni < 4; ++ni) {
                    const int n  = n0 + wc * 64 + ni * 16 + lr;
                    const int bh = b * H + (n >> 6);
                    Op[((size_t)bh * S + s) * DH + (n & 63)] = f2bf(acc[mi][ni][r]);
                }
            }
    }
}

// ---------------------------------------------------------------------------
// Output GEMM, bf16 MFMA (unchanged from round 3).
// ---------------------------------------------------------------------------
__global__ __launch_bounds__(256) void gemm_out(
    const unsigned short* __restrict__ ctxb, const unsigned short* __restrict__ Wot,
    const float* __restrict__ bo, float* __restrict__ out)
{
    __shared__ unsigned short As[64 * 32];
    __shared__ unsigned short Bs[128 * 32];

    const int tid = threadIdx.x;
    const int l  = tid & 63;
    const int w  = tid >> 6;
    const int lr = l & 15;
    const int g  = l >> 4;
    const int wr = w >> 1, wc = w & 1;

    const int m0 = blockIdx.y * 64;
    const int n0 = blockIdx.x * 128;

    const int srow  = tid >> 2;
    const int sslot = tid & 3;
    const int rslot = g ^ ((lr >> 2) & 3);

    f32x4 acc[2][4];
    #pragma unroll
    for (int i = 0; i < 2; ++i)
        #pragma unroll
        for (int j = 0; j < 4; ++j) acc[i][j] = (f32x4){0.f, 0.f, 0.f, 0.f};

    bf16x8 ra, rb[2];
    const int gsA = sslot ^ ((srow >> 2) & 3);
    int gsB[2];
    #pragma unroll
    for (int p = 0; p < 2; ++p) gsB[p] = sslot ^ (((p * 64 + srow) >> 2) & 3);

    ra = *(const bf16x8*)&ctxb[(size_t)(m0 + srow) * D + gsA * 8];
    #pragma unroll
    for (int p = 0; p < 2; ++p)
        rb[p] = *(const bf16x8*)&Wot[(size_t)(n0 + p * 64 + srow) * D + gsB[p] * 8];

    for (int k0 = 0; k0 < D; k0 += 32) {
        __syncthreads();
        *(bf16x8*)&As[srow * 32 + sslot * 8] = ra;
        #pragma unroll
        for (int p = 0; p < 2; ++p)
            *(bf16x8*)&Bs[(p * 64 + srow) * 32 + sslot * 8] = rb[p];
        __syncthreads();
        if (k0 + 32 < D) {
            ra = *(const bf16x8*)&ctxb[(size_t)(m0 + srow) * D + k0 + 32 + gsA * 8];
            #pragma unroll
            for (int p = 0; p < 2; ++p)
                rb[p] = *(const bf16x8*)&Wot[(size_t)(n0 + p * 64 + srow) * D + k0 + 32 + gsB[p] * 8];
        }
        bf16x8 af[2], bfr[4];
        #pragma unroll
        for (int i = 0; i < 2; ++i)
            af[i] = *(const bf16x8*)&As[(wr * 32 + i * 16 + lr) * 32 + rslot * 8];
        #pragma unroll
        for (int i = 0; i < 4; ++i)
            bfr[i] = *(const bf16x8*)&Bs[(wc * 64 + i * 16 + lr) * 32 + rslot * 8];
        #pragma unroll
        for (int mi = 0; mi < 2; ++mi)
            #pragma unroll
            for (int ni = 0; ni < 4; ++ni)
                acc[mi][ni] = __builtin_amdgcn_mfma_f32_16x16x32_bf16(
                    af[mi], bfr[ni], acc[mi][ni], 0, 0, 0);
    }

    #pragma unroll
    for (int mi = 0; mi < 2; ++mi)
        #pragma unroll
        for (int ni = 0; ni < 4; ++ni) {
            const int n = n0 + wc * 64 + ni * 16 + lr;
            const float bias = bo[n];
            #pragma unroll
            for (int r = 0; r < 4; ++r) {
                const int m = m0 + wr * 32 + mi * 16 + g * 4 + r;
                out[(size_t)m * D + n] = acc[mi][ni][r] + bias;
            }
        }
}

// ---------------------------------------------------------------------------
// Causal flash attention, 32x32x16 bf16 MFMA, swapped operands.
// One wave per block, 32 q-rows per wave. Lane owns q-column q0+(lane&31);
// softmax stats are lane-local (one shfl_xor(32) per reduction). PV consumes
// P in-register (one shfl_xor + selects per 16-k chunk). Defer-max THR=8.
//   S^T = mfma(A=K rows, B=Q^T):  C col = q' = lane&31,
//   row kv' = (reg&3) + 8*(reg>>2) + 4*(lane>>5)   [m74/m101 layout]
//   O^T = mfma(A=V^T rows, B=P^T) accumulated per 32-d block.
// ---------------------------------------------------------------------------
template<bool DIAG>
__device__ __forceinline__ void attn_tile(
    const unsigned short* __restrict__ Kp, const unsigned short* __restrict__ Vp,
    int kv0, int l31, int hi,
    const bf16x8 (&qf)[4], f32x16& acc0, f32x16& acc1, float& m, float& ll)
{
    // QK^T: 4 k-chunks of 16
    f32x16 st = {};
    #pragma unroll
    for (int kk = 0; kk < 4; ++kk) {
        bf16x8 kf = *(const bf16x8*)&Kp[(size_t)(kv0 + l31) * DH + kk * 16 + hi * 8];
        st = __builtin_amdgcn_mfma_f32_32x32x16_bf16(kf, qf[kk], st, 0, 0, 0);
    }
    // V^T fragments for PV: vf[dblk][c]
    bf16x8 vf[2][2];
    #pragma unroll
    for (int dblk = 0; dblk < 2; ++dblk)
        #pragma unroll
        for (int c = 0; c < 2; ++c)
            vf[dblk][c] = *(const bf16x8*)&Vp[(size_t)(dblk * 32 + l31) * S + kv0 + c * 16 + hi * 8];

    // scores (this lane's q-column), causal mask only on diagonal tile
    float s[16];
    #pragma unroll
    for (int r = 0; r < 16; ++r) {
        float sv = st[r] * 0.125f;                 // 1/sqrt(64)
        if (DIAG) {
            const int rvoff = (r & 3) + 8 * (r >> 2) + 4 * hi;
            if (rvoff > l31) sv = -3e38f;
        }
        s[r] = sv;
    }
    float pmax = s[0];
    #pragma unroll
    for (int r = 1; r < 16; ++r) pmax = fmaxf(pmax, s[r]);
    pmax = fmaxf(pmax, __shfl_xor(pmax, 32));

    if (!__all(pmax <= m + 8.f)) {                 // T13 defer-max
        const float newm = fmaxf(m, pmax);
        const float corr = __expf(m - newm);
        ll *= corr;
        #pragma unroll
        for (int r = 0; r < 16; ++r) { acc0[r] *= corr; acc1[r] *= corr; }
        m = newm;
    }
    float p[16], psum = 0.f;
    #pragma unroll
    for (int r = 0; r < 16; ++r) { p[r] = __expf(s[r] - m); psum += p[r]; }
    ll += psum + __shfl_xor(psum, 32);

    // pack P pairs: w[t] = bf16x2(p[2t], p[2t+1]); w[t] covers kv pairs
    // (hi=0): w0={0,1} w1={2,3} w2={8,9} w3={10,11} w4={16,17}... (+4 for hi=1)
    unsigned w[8];
    #pragma unroll
    for (int t = 0; t < 8; ++t) w[t] = cvt_pk_bf16(p[2 * t], p[2 * t + 1]);

    // PV: per 16-k chunk c, B-frag words b0..b3 need kv = c*16 + 8*hi + {0..7}.
    // Cross-half exchange via shfl_xor(32): send (hi? wA : wB), receive partner's.
    #pragma unroll
    for (int c = 0; c < 2; ++c) {
        const unsigned wA0 = w[c * 4 + 0], wB0 = w[c * 4 + 2];
        const unsigned wA1 = w[c * 4 + 1], wB1 = w[c * 4 + 3];
        const unsigned t0 = __shfl_xor(hi ? wA0 : wB0, 32);
        const unsigned t1 = __shfl_xor(hi ? wA1 : wB1, 32);
        union { unsigned u[4]; bf16x8 v; } pb;
        pb.u[0] = hi ? t0  : wA0;     // b0
        pb.u[1] = hi ? t1  : wA1;     // b1
        pb.u[2] = hi ? wB0 : t0;      // b2
        pb.u[3] = hi ? wB1 : t1;      // b3
        acc0 = __builtin_amdgcn_mfma_f32_32x32x16_bf16(vf[0][c], pb.v, acc0, 0, 0, 0);
        acc1 = __builtin_amdgcn_mfma_f32_32x32x16_bf16(vf[1][c], pb.v, acc1, 0, 0, 0);
    }
}

__global__ __launch_bounds__(64) void attn_mfma32(
    const unsigned short* __restrict__ Qb, const unsigned short* __restrict__ Kb,
    const unsigned short* __restrict__ Vt, unsigned short* __restrict__ ctxb)
{
    const int l   = threadIdx.x;
    const int l31 = l & 31;
    const int hi  = l >> 5;
    const int qt  = (int)gridDim.x - 1 - (int)blockIdx.x;   // heavy tiles first
    const int bh  = blockIdx.y;
    const int q0  = qt * 32;

    const unsigned short* Qp = Qb + (size_t)bh * S * DH;
    const unsigned short* Kp = Kb + (size_t)bh * S * DH;
    const unsigned short* Vp = Vt + (size_t)bh * DH * S;

    bf16x8 qf[4];
    #pragma unroll
    for (int kk = 0; kk < 4; ++kk)
        qf[kk] = *(const bf16x8*)&Qp[(size_t)(q0 + l31) * DH + kk * 16 + hi * 8];

    f32x16 acc0 = {}, acc1 = {};
    float m = -1e30f, ll = 0.f;

    for (int kt = 0; kt < qt; ++kt)
        attn_tile<false>(Kp, Vp, kt * 32, l31, hi, qf, acc0, acc1, m, ll);
    attn_tile<true>(Kp, Vp, q0, l31, hi, qf, acc0, acc1, m, ll);

    // epilogue: O^T rows d = dblk*32 + rv(reg,hi), col q = q0+l31 (lane-local l)
    const float inv = 1.f / ll;
    const int bb = bh >> 4, hh = bh & (H - 1);
    const int q  = q0 + l31;
    unsigned short* op = ctxb + ((size_t)(bb * S + q)) * D + hh * DH;
    #pragma unroll
    for (int t = 0; t < 8; ++t) {
        const int d = ((2 * t) & 3) + 8 * ((2 * t) >> 2) + 4 * hi;  // even
        *(unsigned*)&op[d]      = cvt_pk_bf16(acc0[2 * t] * inv, acc0[2 * t + 1] * inv);
        *(unsigned*)&op[32 + d] = cvt_pk_bf16(acc1[2 * t] * inv, acc1[2 * t + 1] * inv);
    }
}

} // namespace

extern "C" void kernel_launch(void* const* d_in, const int* in_sizes, int n_in,
                              void* d_out, int out_size, void* d_ws, size_t ws_size,
                              hipStream_t stream) {
    const float* x  = (const float*)d_in[0];
    const float* Wq = (const float*)d_in[1];
    const float* Wk = (const float*)d_in[2];
    const float* Wv = (const float*)d_in[3];
    const float* Wo = (const float*)d_in[4];
    const float* bo = (const float*)d_in[5];
    float* out = (float*)d_out;

    // ws (bf16): xb 8MB | Wt 4x2MB | Qb 8MB | Kb 8MB | Vt 8MB | ctxb 8MB = 48MB
    unsigned short* xb   = (unsigned short*)d_ws;
    unsigned short* Wt   = xb + (size_t)M * D;
    unsigned short* Qb   = Wt + (size_t)4 * D * D;
    unsigned short* Kb   = Qb + (size_t)M * D;
    unsigned short* Vtp  = Kb + (size_t)M * D;
    unsigned short* ctxb = Vtp + (size_t)M * D;

    convert_x<<<dim3((M * D) / (256 * 8)), 256, 0, stream>>>(x, xb);
    convert_w<<<dim3(D / 8, D / 64, 4), 64, 0, stream>>>(Wq, Wk, Wv, Wo, Wt);
    gemm_qkv<<<dim3(24, M / 128), 256, 0, stream>>>(xb, Wt, Qb, Kb, Vtp);
    attn_mfma32<<<dim3(S / 32, B * H), 64, 0, stream>>>(Qb, Kb, Vtp, ctxb);
    gemm_out<<<dim3(D / 128, M / 64), 256, 0, stream>>>(
        ctxb, Wt + (size_t)3 * D * D, bo, out);
}

// Round 5
// 255.384 us; speedup vs baseline: 10.0733x; 1.0400x over previous
//
#include <hip/hip_runtime.h>
#include <math.h>

namespace {

constexpr int S   = 2048;
constexpr int D   = 1024;   // d_model (= K for all GEMMs)
constexpr int H   = 16;     // heads
constexpr int DH  = 64;     // head dim
constexpr int B   = 2;      // batch
constexpr int M   = B * S;  // 4096 rows

typedef __attribute__((ext_vector_type(8)))  short bf16x8;   // 8 bf16 = 4 VGPR
typedef __attribute__((ext_vector_type(4)))  float f32x4;
typedef __attribute__((ext_vector_type(16))) float f32x16;

__device__ __forceinline__ unsigned short f2bf(float f) {
    unsigned u = __builtin_bit_cast(unsigned, f);
    u += 0x7fffu + ((u >> 16) & 1u);          // round-to-nearest-even
    return (unsigned short)(u >> 16);
}

__device__ __forceinline__ unsigned cvt_pk_bf16(float lo, float hi) {
    unsigned r;
    asm("v_cvt_pk_bf16_f32 %0, %1, %2" : "=v"(r) : "v"(lo), "v"(hi));
    return r;
}

// ---------------------------------------------------------------------------
// convert_x: x fp32 [4096][1024] -> bf16
// ---------------------------------------------------------------------------
__global__ __launch_bounds__(256) void convert_x(
    const float* __restrict__ x, unsigned short* __restrict__ xb)
{
    const int i = (blockIdx.x * 256 + threadIdx.x) * 8;
    float4 a = *(const float4*)&x[i];
    float4 b = *(const float4*)&x[i + 4];
    ushort4 lo, hi;
    lo.x = f2bf(a.x); lo.y = f2bf(a.y); lo.z = f2bf(a.z); lo.w = f2bf(a.w);
    hi.x = f2bf(b.x); hi.y = f2bf(b.y); hi.z = f2bf(b.z); hi.w = f2bf(b.w);
    *(ushort4*)&xb[i]     = lo;
    *(ushort4*)&xb[i + 4] = hi;
}

// ---------------------------------------------------------------------------
// convert_w: W fp32 [k][n] -> Wt bf16 [mat][n][k] (transposed, n-major)
// ---------------------------------------------------------------------------
__global__ __launch_bounds__(64) void convert_w(
    const float* __restrict__ Wq, const float* __restrict__ Wk,
    const float* __restrict__ Wv, const float* __restrict__ Wo,
    unsigned short* __restrict__ Wt)
{
    const int mat = blockIdx.z;
    const float* W = (mat == 0) ? Wq : (mat == 1) ? Wk : (mat == 2) ? Wv : Wo;
    const int n  = blockIdx.y * 64 + threadIdx.x;
    const int k0 = blockIdx.x * 8;
    ushort4 u0, u1;
    u0.x = f2bf(W[(size_t)(k0 + 0) * D + n]);
    u0.y = f2bf(W[(size_t)(k0 + 1) * D + n]);
    u0.z = f2bf(W[(size_t)(k0 + 2) * D + n]);
    u0.w = f2bf(W[(size_t)(k0 + 3) * D + n]);
    u1.x = f2bf(W[(size_t)(k0 + 4) * D + n]);
    u1.y = f2bf(W[(size_t)(k0 + 5) * D + n]);
    u1.z = f2bf(W[(size_t)(k0 + 6) * D + n]);
    u1.w = f2bf(W[(size_t)(k0 + 7) * D + n]);
    unsigned short* o = Wt + (size_t)mat * D * D + (size_t)n * D + k0;
    *(ushort4*)&o[0] = u0;
    *(ushort4*)&o[4] = u1;
}

// ---------------------------------------------------------------------------
// QKV GEMM, bf16 MFMA 16x16x32 (unchanged).
// ---------------------------------------------------------------------------
__global__ __launch_bounds__(256) void gemm_qkv(
    const unsigned short* __restrict__ xb, const unsigned short* __restrict__ Wt,
    unsigned short* __restrict__ Qb, unsigned short* __restrict__ Kb,
    unsigned short* __restrict__ Vt)
{
    __shared__ unsigned short As[128 * 32];
    __shared__ unsigned short Bs[128 * 32];

    const int tid = threadIdx.x;
    const int l  = tid & 63;
    const int w  = tid >> 6;
    const int lr = l & 15;
    const int g  = l >> 4;
    const int wr = w >> 1, wc = w & 1;

    const int bm  = blockIdx.y;
    const int bnl = blockIdx.x;          // 0..23
    const int mat = bnl >> 3;            // 0..2
    const int n0  = (bnl & 7) * 128;
    const int m0  = bm * 128;
    const unsigned short* Bp = Wt + (size_t)mat * D * D;

    const int srow  = tid >> 2;
    const int sslot = tid & 3;
    const int rslot = g ^ ((lr >> 2) & 3);

    f32x4 acc[4][4];
    #pragma unroll
    for (int i = 0; i < 4; ++i)
        #pragma unroll
        for (int j = 0; j < 4; ++j) acc[i][j] = (f32x4){0.f, 0.f, 0.f, 0.f};

    bf16x8 ra[2], rb[2];
    int gs[2];
    #pragma unroll
    for (int p = 0; p < 2; ++p) gs[p] = sslot ^ (((p * 64 + srow) >> 2) & 3);

    #pragma unroll
    for (int p = 0; p < 2; ++p) {
        const int row = p * 64 + srow;
        ra[p] = *(const bf16x8*)&xb[(size_t)(m0 + row) * D + gs[p] * 8];
        rb[p] = *(const bf16x8*)&Bp[(size_t)(n0 + row) * D + gs[p] * 8];
    }

    for (int k0 = 0; k0 < D; k0 += 32) {
        __syncthreads();
        #pragma unroll
        for (int p = 0; p < 2; ++p) {
            const int row = p * 64 + srow;
            *(bf16x8*)&As[row * 32 + sslot * 8] = ra[p];
            *(bf16x8*)&Bs[row * 32 + sslot * 8] = rb[p];
        }
        __syncthreads();
        if (k0 + 32 < D) {
            #pragma unroll
            for (int p = 0; p < 2; ++p) {
                const int row = p * 64 + srow;
                ra[p] = *(const bf16x8*)&xb[(size_t)(m0 + row) * D + k0 + 32 + gs[p] * 8];
                rb[p] = *(const bf16x8*)&Bp[(size_t)(n0 + row) * D + k0 + 32 + gs[p] * 8];
            }
        }
        bf16x8 af[4], bfr[4];
        #pragma unroll
        for (int i = 0; i < 4; ++i) {
            af[i]  = *(const bf16x8*)&As[(wr * 64 + i * 16 + lr) * 32 + rslot * 8];
            bfr[i] = *(const bf16x8*)&Bs[(wc * 64 + i * 16 + lr) * 32 + rslot * 8];
        }
        #pragma unroll
        for (int mi = 0; mi < 4; ++mi)
            #pragma unroll
            for (int ni = 0; ni < 4; ++ni)
                acc[mi][ni] = __builtin_amdgcn_mfma_f32_16x16x32_bf16(
                    af[mi], bfr[ni], acc[mi][ni], 0, 0, 0);
    }

    const int b      = m0 >> 11;
    const int s_base = (m0 & (S - 1)) + wr * 64;
    if (mat == 2) {
        #pragma unroll
        for (int ni = 0; ni < 4; ++ni) {
            const int n  = n0 + wc * 64 + ni * 16 + lr;
            const int bh = b * H + (n >> 6);
            unsigned short* vp = Vt + ((size_t)bh * DH + (n & 63)) * S;
            #pragma unroll
            for (int mi = 0; mi < 4; ++mi) {
                const int s0 = s_base + mi * 16 + g * 4;
                ushort4 u;
                u.x = f2bf(acc[mi][ni][0]); u.y = f2bf(acc[mi][ni][1]);
                u.z = f2bf(acc[mi][ni][2]); u.w = f2bf(acc[mi][ni][3]);
                *(ushort4*)&vp[s0] = u;
            }
        }
    } else {
        unsigned short* Op = (mat == 0) ? Qb : Kb;
        #pragma unroll
        for (int mi = 0; mi < 4; ++mi)
            #pragma unroll
            for (int r = 0; r < 4; ++r) {
                const int s = s_base + mi * 16 + g * 4 + r;
                #pragma unroll
                for (int ni = 0; ni < 4; ++ni) {
                    const int n  = n0 + wc * 64 + ni * 16 + lr;
                    const int bh = b * H + (n >> 6);
                    Op[((size_t)bh * S + s) * DH + (n & 63)] = f2bf(acc[mi][ni][r]);
                }
            }
    }
}

// ---------------------------------------------------------------------------
// Output GEMM, bf16 MFMA (unchanged).
// ---------------------------------------------------------------------------
__global__ __launch_bounds__(256) void gemm_out(
    const unsigned short* __restrict__ ctxb, const unsigned short* __restrict__ Wot,
    const float* __restrict__ bo, float* __restrict__ out)
{
    __shared__ unsigned short As[64 * 32];
    __shared__ unsigned short Bs[128 * 32];

    const int tid = threadIdx.x;
    const int l  = tid & 63;
    const int w  = tid >> 6;
    const int lr = l & 15;
    const int g  = l >> 4;
    const int wr = w >> 1, wc = w & 1;

    const int m0 = blockIdx.y * 64;
    const int n0 = blockIdx.x * 128;

    const int srow  = tid >> 2;
    const int sslot = tid & 3;
    const int rslot = g ^ ((lr >> 2) & 3);

    f32x4 acc[2][4];
    #pragma unroll
    for (int i = 0; i < 2; ++i)
        #pragma unroll
        for (int j = 0; j < 4; ++j) acc[i][j] = (f32x4){0.f, 0.f, 0.f, 0.f};

    bf16x8 ra, rb[2];
    const int gsA = sslot ^ ((srow >> 2) & 3);
    int gsB[2];
    #pragma unroll
    for (int p = 0; p < 2; ++p) gsB[p] = sslot ^ (((p * 64 + srow) >> 2) & 3);

    ra = *(const bf16x8*)&ctxb[(size_t)(m0 + srow) * D + gsA * 8];
    #pragma unroll
    for (int p = 0; p < 2; ++p)
        rb[p] = *(const bf16x8*)&Wot[(size_t)(n0 + p * 64 + srow) * D + gsB[p] * 8];

    for (int k0 = 0; k0 < D; k0 += 32) {
        __syncthreads();
        *(bf16x8*)&As[srow * 32 + sslot * 8] = ra;
        #pragma unroll
        for (int p = 0; p < 2; ++p)
            *(bf16x8*)&Bs[(p * 64 + srow) * 32 + sslot * 8] = rb[p];
        __syncthreads();
        if (k0 + 32 < D) {
            ra = *(const bf16x8*)&ctxb[(size_t)(m0 + srow) * D + k0 + 32 + gsA * 8];
            #pragma unroll
            for (int p = 0; p < 2; ++p)
                rb[p] = *(const bf16x8*)&Wot[(size_t)(n0 + p * 64 + srow) * D + k0 + 32 + gsB[p] * 8];
        }
        bf16x8 af[2], bfr[4];
        #pragma unroll
        for (int i = 0; i < 2; ++i)
            af[i] = *(const bf16x8*)&As[(wr * 32 + i * 16 + lr) * 32 + rslot * 8];
        #pragma unroll
        for (int i = 0; i < 4; ++i)
            bfr[i] = *(const bf16x8*)&Bs[(wc * 64 + i * 16 + lr) * 32 + rslot * 8];
        #pragma unroll
        for (int mi = 0; mi < 2; ++mi)
            #pragma unroll
            for (int ni = 0; ni < 4; ++ni)
                acc[mi][ni] = __builtin_amdgcn_mfma_f32_16x16x32_bf16(
                    af[mi], bfr[ni], acc[mi][ni], 0, 0, 0);
    }

    #pragma unroll
    for (int mi = 0; mi < 2; ++mi)
        #pragma unroll
        for (int ni = 0; ni < 4; ++ni) {
            const int n = n0 + wc * 64 + ni * 16 + lr;
            const float bias = bo[n];
            #pragma unroll
            for (int r = 0; r < 4; ++r) {
                const int m = m0 + wr * 32 + mi * 16 + g * 4 + r;
                out[(size_t)m * D + n] = acc[mi][ni][r] + bias;
            }
        }
}

// ---------------------------------------------------------------------------
// Causal flash attention, 32x32x16 bf16 MFMA, swapped operands, split-KV x2.
// 128-thread block = 2 waves on the SAME 32 q-rows: wave0 does KV tiles
// [0,h), wave1 does [h,nt) incl. diagonal. Wave0 parks partial (m,l,acc) in
// LDS; wave1 merges (online-softmax combine) and writes ctx. Doubles wave
// parallelism and halves the longest serial chain (the round-4 limiter).
// ---------------------------------------------------------------------------
template<bool DIAG>
__device__ __forceinline__ void attn_tile(
    const unsigned short* __restrict__ Kp, const unsigned short* __restrict__ Vp,
    int kv0, int l31, int hi,
    const bf16x8 (&qf)[4], f32x16& acc0, f32x16& acc1, float& m, float& ll)
{
    // clustered loads: all K and V fragments issue as one batch
    bf16x8 kf[4];
    #pragma unroll
    for (int kk = 0; kk < 4; ++kk)
        kf[kk] = *(const bf16x8*)&Kp[(size_t)(kv0 + l31) * DH + kk * 16 + hi * 8];
    bf16x8 vf[2][2];
    #pragma unroll
    for (int dblk = 0; dblk < 2; ++dblk)
        #pragma unroll
        for (int c = 0; c < 2; ++c)
            vf[dblk][c] = *(const bf16x8*)&Vp[(size_t)(dblk * 32 + l31) * S + kv0 + c * 16 + hi * 8];

    // QK^T with two partial accumulators (chain depth 2, not 4)
    f32x16 st0 = {}, st1 = {};
    st0 = __builtin_amdgcn_mfma_f32_32x32x16_bf16(kf[0], qf[0], st0, 0, 0, 0);
    st1 = __builtin_amdgcn_mfma_f32_32x32x16_bf16(kf[2], qf[2], st1, 0, 0, 0);
    st0 = __builtin_amdgcn_mfma_f32_32x32x16_bf16(kf[1], qf[1], st0, 0, 0, 0);
    st1 = __builtin_amdgcn_mfma_f32_32x32x16_bf16(kf[3], qf[3], st1, 0, 0, 0);

    float s[16];
    #pragma unroll
    for (int r = 0; r < 16; ++r) {
        float sv = (st0[r] + st1[r]) * 0.125f;     // 1/sqrt(64)
        if (DIAG) {
            const int rvoff = (r & 3) + 8 * (r >> 2) + 4 * hi;
            if (rvoff > l31) sv = -3e38f;
        }
        s[r] = sv;
    }
    float pmax = s[0];
    #pragma unroll
    for (int r = 1; r < 16; ++r) pmax = fmaxf(pmax, s[r]);
    pmax = fmaxf(pmax, __shfl_xor(pmax, 32));

    if (!__all(pmax <= m + 8.f)) {                 // T13 defer-max
        const float newm = fmaxf(m, pmax);
        const float corr = __expf(m - newm);
        ll *= corr;
        #pragma unroll
        for (int r = 0; r < 16; ++r) { acc0[r] *= corr; acc1[r] *= corr; }
        m = newm;
    }
    float p[16], psum = 0.f;
    #pragma unroll
    for (int r = 0; r < 16; ++r) { p[r] = __expf(s[r] - m); psum += p[r]; }
    ll += psum + __shfl_xor(psum, 32);

    unsigned w[8];
    #pragma unroll
    for (int t = 0; t < 8; ++t) w[t] = cvt_pk_bf16(p[2 * t], p[2 * t + 1]);

    #pragma unroll
    for (int c = 0; c < 2; ++c) {
        const unsigned wA0 = w[c * 4 + 0], wB0 = w[c * 4 + 2];
        const unsigned wA1 = w[c * 4 + 1], wB1 = w[c * 4 + 3];
        const unsigned t0 = __shfl_xor(hi ? wA0 : wB0, 32);
        const unsigned t1 = __shfl_xor(hi ? wA1 : wB1, 32);
        union { unsigned u[4]; bf16x8 v; } pb;
        pb.u[0] = hi ? t0  : wA0;
        pb.u[1] = hi ? t1  : wA1;
        pb.u[2] = hi ? wB0 : t0;
        pb.u[3] = hi ? wB1 : t1;
        acc0 = __builtin_amdgcn_mfma_f32_32x32x16_bf16(vf[0][c], pb.v, acc0, 0, 0, 0);
        acc1 = __builtin_amdgcn_mfma_f32_32x32x16_bf16(vf[1][c], pb.v, acc1, 0, 0, 0);
    }
}

__global__ __launch_bounds__(128) void attn_mfma32(
    const unsigned short* __restrict__ Qb, const unsigned short* __restrict__ Kb,
    const unsigned short* __restrict__ Vt, unsigned short* __restrict__ ctxb)
{
    __shared__ float smerge[64][36];     // 16B-aligned rows; one-shot merge buffer

    const int tid = threadIdx.x;
    const int l   = tid & 63;
    const int wv  = tid >> 6;            // 0 = front half of KV, 1 = back half
    const int l31 = l & 31;
    const int hi  = (l >> 5) & 1;
    const int qt  = (int)gridDim.x - 1 - (int)blockIdx.x;   // heavy tiles first
    const int bh  = blockIdx.y;
    const int q0  = qt * 32;
    const int nt  = qt + 1;
    const int h   = nt >> 1;             // wave0: [0,h)  wave1: [h,nt)

    const unsigned short* Qp = Qb + (size_t)bh * S * DH;
    const unsigned short* Kp = Kb + (size_t)bh * S * DH;
    const unsigned short* Vp = Vt + (size_t)bh * DH * S;

    bf16x8 qf[4];
    #pragma unroll
    for (int kk = 0; kk < 4; ++kk)
        qf[kk] = *(const bf16x8*)&Qp[(size_t)(q0 + l31) * DH + kk * 16 + hi * 8];

    f32x16 acc0 = {}, acc1 = {};
    float m = -1e30f, ll = 0.f;

    if (wv == 0) {
        for (int kt = 0; kt < h; ++kt)
            attn_tile<false>(Kp, Vp, kt * 32, l31, hi, qf, acc0, acc1, m, ll);
        #pragma unroll
        for (int r = 0; r < 16; ++r) {
            smerge[l][r]      = acc0[r];
            smerge[l][16 + r] = acc1[r];
        }
        smerge[l][32] = m;
        smerge[l][33] = ll;
    } else {
        for (int kt = h; kt < qt; ++kt)
            attn_tile<false>(Kp, Vp, kt * 32, l31, hi, qf, acc0, acc1, m, ll);
        attn_tile<true>(Kp, Vp, q0, l31, hi, qf, acc0, acc1, m, ll);
    }
    __syncthreads();

    if (wv == 1) {
        const float mA = smerge[l][32], lA = smerge[l][33];
        const float ms = fmaxf(m, mA);
        const float cB = __expf(m - ms);
        const float cA = __expf(mA - ms);
        const float lsum = ll * cB + lA * cA;
        const float inv  = 1.f / lsum;

        const int bb = bh >> 4, hh = bh & (H - 1);
        const int q  = q0 + l31;
        unsigned short* op = ctxb + ((size_t)(bb * S + q)) * D + hh * DH;
        #pragma unroll
        for (int t = 0; t < 8; ++t) {
            const int r0 = 2 * t, r1 = 2 * t + 1;
            const int d  = (r0 & 3) + 8 * (r0 >> 2) + 4 * hi;   // even reg -> d, d+1
            const float a0 = (acc0[r0] * cB + smerge[l][r0]      * cA) * inv;
            const float a1 = (acc0[r1] * cB + smerge[l][r1]      * cA) * inv;
            const float b0 = (acc1[r0] * cB + smerge[l][16 + r0] * cA) * inv;
            const float b1 = (acc1[r1] * cB + smerge[l][16 + r1] * cA) * inv;
            *(unsigned*)&op[d]      = cvt_pk_bf16(a0, a1);
            *(unsigned*)&op[32 + d] = cvt_pk_bf16(b0, b1);
        }
    }
}

} // namespace

extern "C" void kernel_launch(void* const* d_in, const int* in_sizes, int n_in,
                              void* d_out, int out_size, void* d_ws, size_t ws_size,
                              hipStream_t stream) {
    const float* x  = (const float*)d_in[0];
    const float* Wq = (const float*)d_in[1];
    const float* Wk = (const float*)d_in[2];
    const float* Wv = (const float*)d_in[3];
    const float* Wo = (const float*)d_in[4];
    const float* bo = (const float*)d_in[5];
    float* out = (float*)d_out;

    // ws (bf16): xb 8MB | Wt 4x2MB | Qb 8MB | Kb 8MB | Vt 8MB | ctxb 8MB = 48MB
    unsigned short* xb   = (unsigned short*)d_ws;
    unsigned short* Wt   = xb + (size_t)M * D;
    unsigned short* Qb   = Wt + (size_t)4 * D * D;
    unsigned short* Kb   = Qb + (size_t)M * D;
    unsigned short* Vtp  = Kb + (size_t)M * D;
    unsigned short* ctxb = Vtp + (size_t)M * D;

    convert_x<<<dim3((M * D) / (256 * 8)), 256, 0, stream>>>(x, xb);
    convert_w<<<dim3(D / 8, D / 64, 4), 64, 0, stream>>>(Wq, Wk, Wv, Wo, Wt);
    gemm_qkv<<<dim3(24, M / 128), 256, 0, stream>>>(xb, Wt, Qb, Kb, Vtp);
    attn_mfma32<<<dim3(S / 32, B * H), 128, 0, stream>>>(Qb, Kb, Vtp, ctxb);
    gemm_out<<<dim3(D / 128, M / 64), 256, 0, stream>>>(
        ctxb, Wt + (size_t)3 * D * D, bo, out);
}

// Round 7
// 226.702 us; speedup vs baseline: 11.3477x; 1.1265x over previous
//
#include <hip/hip_runtime.h>
#include <math.h>

namespace {

constexpr int S   = 2048;
constexpr int D   = 1024;   // d_model (= K for all GEMMs)
constexpr int H   = 16;     // heads
constexpr int DH  = 64;     // head dim
constexpr int B   = 2;      // batch
constexpr int M   = B * S;  // 4096 rows

typedef __attribute__((ext_vector_type(8)))  short bf16x8;   // 8 bf16 = 4 VGPR
typedef __attribute__((ext_vector_type(4)))  float f32x4;
typedef __attribute__((ext_vector_type(16))) float f32x16;

__device__ __forceinline__ unsigned short f2bf(float f) {
    unsigned u = __builtin_bit_cast(unsigned, f);
    u += 0x7fffu + ((u >> 16) & 1u);          // round-to-nearest-even
    return (unsigned short)(u >> 16);
}

__device__ __forceinline__ unsigned cvt_pk_bf16(float lo, float hi) {
    unsigned r;
    asm("v_cvt_pk_bf16_f32 %0, %1, %2" : "=v"(r) : "v"(lo), "v"(hi));
    return r;
}

// async global->LDS, 16B per lane. LDS dest = wave-uniform base + lane*16.
__device__ __forceinline__ void gload16(const void* g, void* l) {
    __builtin_amdgcn_global_load_lds(
        (const __attribute__((address_space(1))) void*)g,
        (__attribute__((address_space(3))) void*)l, 16, 0, 0);
}

// ---------------------------------------------------------------------------
// convert_x: x fp32 [4096][1024] -> bf16
// ---------------------------------------------------------------------------
__global__ __launch_bounds__(256) void convert_x(
    const float* __restrict__ x, unsigned short* __restrict__ xb)
{
    const int i = (blockIdx.x * 256 + threadIdx.x) * 8;
    float4 a = *(const float4*)&x[i];
    float4 b = *(const float4*)&x[i + 4];
    ushort4 lo, hi;
    lo.x = f2bf(a.x); lo.y = f2bf(a.y); lo.z = f2bf(a.z); lo.w = f2bf(a.w);
    hi.x = f2bf(b.x); hi.y = f2bf(b.y); hi.z = f2bf(b.z); hi.w = f2bf(b.w);
    *(ushort4*)&xb[i]     = lo;
    *(ushort4*)&xb[i + 4] = hi;
}

// ---------------------------------------------------------------------------
// convert_w: W fp32 [k][n] -> Wt bf16 [mat][n][k] (transposed, n-major)
// ---------------------------------------------------------------------------
__global__ __launch_bounds__(64) void convert_w(
    const float* __restrict__ Wq, const float* __restrict__ Wk,
    const float* __restrict__ Wv, const float* __restrict__ Wo,
    unsigned short* __restrict__ Wt)
{
    const int mat = blockIdx.z;
    const float* W = (mat == 0) ? Wq : (mat == 1) ? Wk : (mat == 2) ? Wv : Wo;
    const int n  = blockIdx.y * 64 + threadIdx.x;
    const int k0 = blockIdx.x * 8;
    ushort4 u0, u1;
    u0.x = f2bf(W[(size_t)(k0 + 0) * D + n]);
    u0.y = f2bf(W[(size_t)(k0 + 1) * D + n]);
    u0.z = f2bf(W[(size_t)(k0 + 2) * D + n]);
    u0.w = f2bf(W[(size_t)(k0 + 3) * D + n]);
    u1.x = f2bf(W[(size_t)(k0 + 4) * D + n]);
    u1.y = f2bf(W[(size_t)(k0 + 5) * D + n]);
    u1.z = f2bf(W[(size_t)(k0 + 6) * D + n]);
    u1.w = f2bf(W[(size_t)(k0 + 7) * D + n]);
    unsigned short* o = Wt + (size_t)mat * D * D + (size_t)n * D + k0;
    *(ushort4*)&o[0] = u0;
    *(ushort4*)&o[4] = u1;
}

// ---------------------------------------------------------------------------
// QKV GEMM, bf16 MFMA 16x16x32. 128x128 tile, BK=32, 4 waves (2x2).
// Staging via global_load_lds (width 16), linear LDS [row][32] (64B rows:
// read pattern uses all 32 banks at the 1KB/instr floor - no swizzle needed).
// ---------------------------------------------------------------------------
__global__ __launch_bounds__(256) void gemm_qkv(
    const unsigned short* __restrict__ xb, const unsigned short* __restrict__ Wt,
    unsigned short* __restrict__ Qb, unsigned short* __restrict__ Kb,
    unsigned short* __restrict__ Vt)
{
    __shared__ unsigned short As[128 * 32];
    __shared__ unsigned short Bs[128 * 32];

    const int tid = threadIdx.x;
    const int l  = tid & 63;
    const int w  = tid >> 6;
    const int lr = l & 15;
    const int g  = l >> 4;
    const int wr = w >> 1, wc = w & 1;

    const int bm  = blockIdx.y;
    const int bnl = blockIdx.x;          // 0..23
    const int mat = bnl >> 3;            // 0..2
    const int n0  = (bnl & 7) * 128;
    const int m0  = bm * 128;
    const unsigned short* Bp = Wt + (size_t)mat * D * D;

    const int lrow = l >> 2;             // 0..15 row within 16-row chunk
    const int lcol = (l & 3) * 8;        // 0,8,16,24

    f32x4 acc[4][4];
    #pragma unroll
    for (int i = 0; i < 4; ++i)
        #pragma unroll
        for (int j = 0; j < 4; ++j) acc[i][j] = (f32x4){0.f, 0.f, 0.f, 0.f};

    for (int k0 = 0; k0 < D; k0 += 32) {
        #pragma unroll
        for (int p = 0; p < 2; ++p) {
            const int c = w * 2 + p;             // chunk 0..7 (16 rows each)
            gload16(&xb[(size_t)(m0 + c * 16 + lrow) * D + k0 + lcol], &As[c * 512]);
            gload16(&Bp[(size_t)(n0 + c * 16 + lrow) * D + k0 + lcol], &Bs[c * 512]);
        }
        __syncthreads();                         // vmcnt(0) drain by compiler
        bf16x8 af[4], bfr[4];
        #pragma unroll
        for (int i = 0; i < 4; ++i) {
            af[i]  = *(const bf16x8*)&As[(wr * 64 + i * 16 + lr) * 32 + g * 8];
            bfr[i] = *(const bf16x8*)&Bs[(wc * 64 + i * 16 + lr) * 32 + g * 8];
        }
        #pragma unroll
        for (int mi = 0; mi < 4; ++mi)
            #pragma unroll
            for (int ni = 0; ni < 4; ++ni)
                acc[mi][ni] = __builtin_amdgcn_mfma_f32_16x16x32_bf16(
                    af[mi], bfr[ni], acc[mi][ni], 0, 0, 0);
        __syncthreads();
    }

    const int b      = m0 >> 11;
    const int s_base = (m0 & (S - 1)) + wr * 64;
    if (mat == 2) {
        #pragma unroll
        for (int ni = 0; ni < 4; ++ni) {
            const int n  = n0 + wc * 64 + ni * 16 + lr;
            const int bh = b * H + (n >> 6);
            unsigned short* vp = Vt + ((size_t)bh * DH + (n & 63)) * S;
            #pragma unroll
            for (int mi = 0; mi < 4; ++mi) {
                const int s0 = s_base + mi * 16 + g * 4;
                ushort4 u;
                u.x = f2bf(acc[mi][ni][0]); u.y = f2bf(acc[mi][ni][1]);
                u.z = f2bf(acc[mi][ni][2]); u.w = f2bf(acc[mi][ni][3]);
                *(ushort4*)&vp[s0] = u;
            }
        }
    } else {
        unsigned short* Op = (mat == 0) ? Qb : Kb;
        #pragma unroll
        for (int mi = 0; mi < 4; ++mi)
            #pragma unroll
            for (int r = 0; r < 4; ++r) {
                const int s = s_base + mi * 16 + g * 4 + r;
                #pragma unroll
                for (int ni = 0; ni < 4; ++ni) {
                    const int n  = n0 + wc * 64 + ni * 16 + lr;
                    const int bh = b * H + (n >> 6);
                    Op[((size_t)bh * S + s) * DH + (n & 63)] = f2bf(acc[mi][ni][r]);
                }
            }
    }
}

// ---------------------------------------------------------------------------
// Output GEMM, bf16 MFMA, global_load_lds staging (same pattern).
// ---------------------------------------------------------------------------
__global__ __launch_bounds__(256) void gemm_out(
    const unsigned short* __restrict__ ctxb, const unsigned short* __restrict__ Wot,
    const float* __restrict__ bo, float* __restrict__ out)
{
    __shared__ unsigned short As[64 * 32];
    __shared__ unsigned short Bs[128 * 32];

    const int tid = threadIdx.x;
    const int l  = tid & 63;
    const int w  = tid >> 6;
    const int lr = l & 15;
    const int g  = l >> 4;
    const int wr = w >> 1, wc = w & 1;

    const int m0 = blockIdx.y * 64;
    const int n0 = blockIdx.x * 128;

    const int lrow = l >> 2;
    const int lcol = (l & 3) * 8;

    f32x4 acc[2][4];
    #pragma unroll
    for (int i = 0; i < 2; ++i)
        #pragma unroll
        for (int j = 0; j < 4; ++j) acc[i][j] = (f32x4){0.f, 0.f, 0.f, 0.f};

    for (int k0 = 0; k0 < D; k0 += 32) {
        gload16(&ctxb[(size_t)(m0 + w * 16 + lrow) * D + k0 + lcol], &As[w * 512]);
        #pragma unroll
        for (int p = 0; p < 2; ++p) {
            const int c = w * 2 + p;
            gload16(&Wot[(size_t)(n0 + c * 16 + lrow) * D + k0 + lcol], &Bs[c * 512]);
        }
        __syncthreads();
        bf16x8 af[2], bfr[4];
        #pragma unroll
        for (int i = 0; i < 2; ++i)
            af[i] = *(const bf16x8*)&As[(wr * 32 + i * 16 + lr) * 32 + g * 8];
        #pragma unroll
        for (int i = 0; i < 4; ++i)
            bfr[i] = *(const bf16x8*)&Bs[(wc * 64 + i * 16 + lr) * 32 + g * 8];
        #pragma unroll
        for (int mi = 0; mi < 2; ++mi)
            #pragma unroll
            for (int ni = 0; ni < 4; ++ni)
                acc[mi][ni] = __builtin_amdgcn_mfma_f32_16x16x32_bf16(
                    af[mi], bfr[ni], acc[mi][ni], 0, 0, 0);
        __syncthreads();
    }

    #pragma unroll
    for (int mi = 0; mi < 2; ++mi)
        #pragma unroll
        for (int ni = 0; ni < 4; ++ni) {
            const int n = n0 + wc * 64 + ni * 16 + lr;
            const float bias = bo[n];
            #pragma unroll
            for (int r = 0; r < 4; ++r) {
                const int m = m0 + wr * 32 + mi * 16 + g * 4 + r;
                out[(size_t)m * D + n] = acc[mi][ni][r] + bias;
            }
        }
}

// ---------------------------------------------------------------------------
// Causal flash attention, 32x32x16 bf16 MFMA, swapped operands.
// Block = 4 waves x 32 q-rows = 128 q-rows. KV tiles of 64 double-buffered
// in LDS via global_load_lds; 128B LDS rows XOR-swizzled (slot ^= row&7) with
// the inverse swizzle applied to the per-lane GLOBAL source address (rule 21).
// XCD-swizzled grid: 4 bh per XCD -> KV (2MB) L2-resident.
// ---------------------------------------------------------------------------
__global__ __launch_bounds__(256, 2) void attn_mfma32(
    const unsigned short* __restrict__ Qb, const unsigned short* __restrict__ Kb,
    const unsigned short* __restrict__ Vt, unsigned short* __restrict__ ctxb)
{
    __shared__ unsigned short Ks[2][64 * 64];
    __shared__ unsigned short Vs[2][64 * 64];

    const int tid = threadIdx.x;
    const int l   = tid & 63;
    const int w   = tid >> 6;            // wave 0..3
    const int l31 = l & 31;
    const int hi  = l >> 5;

    // XCD swizzle: blocks with lid%8==k run on XCD k -> give XCD k bh 4k..4k+3
    const int lid = blockIdx.x;          // 0..511
    const int xcd = lid & 7;
    const int jj  = lid >> 3;            // 0..63
    const int bh  = xcd * 4 + (jj >> 4);
    const int qt  = 15 - (jj & 15);      // heavy q-tiles first
    const int q0w = qt * 128 + w * 32;   // this wave's first q-row
    const int Fw  = q0w >> 6;            // this wave's diagonal kv-tile
    const int NT  = 2 * qt + 2;          // kv tiles for the block

    const unsigned short* Qp = Qb + (size_t)bh * S * DH;
    const unsigned short* Kp = Kb + (size_t)bh * S * DH;
    const unsigned short* Vp = Vt + (size_t)bh * DH * S;

    // Q fragments, held whole kernel
    bf16x8 qf[4];
    #pragma unroll
    for (int kk = 0; kk < 4; ++kk)
        qf[kk] = *(const bf16x8*)&Qp[(size_t)(q0w + l31) * DH + kk * 16 + hi * 8];

    f32x16 acc0 = {}, acc1 = {};
    float m = -1e30f, ll = 0.f;

    // staging: tile = 64x64 bf16 (8KB) each for K and V^T; 8 chunks of 1KB
    // (8 rows each); wave w stages chunks {2w, 2w+1} of each.
    // source col pre-swizzled: slot (l&7) ^ (row&7), row&7 == l>>3.
    const int srow = l >> 3;                       // row within chunk (0..7)
    const int ssw  = 8 * ((l & 7) ^ srow);         // swizzled col (elements)

#define ATTN_STAGE(buf, t)                                                    \
    {                                                                         \
        const int kv0s = (t) * 64;                                            \
        _Pragma("unroll")                                                     \
        for (int p = 0; p < 2; ++p) {                                         \
            const int c   = w * 2 + p;                                        \
            const int row = c * 8 + srow;                                     \
            gload16(Kp + (size_t)(kv0s + row) * DH + ssw, &Ks[buf][c * 512]); \
            gload16(Vp + (size_t)row * S + kv0s + ssw, &Vs[buf][c * 512]);    \
        }                                                                     \
    }

    ATTN_STAGE(0, 0);
    __syncthreads();

    for (int t = 0; t < NT; ++t) {
        const int cur = t & 1;
        if (t + 1 < NT) ATTN_STAGE(cur ^ 1, t + 1);

        if (t <= Fw) {                                // wave-uniform
            const int kv0  = t * 64;
            const bool diag = (t == Fw);

            // QK^T: two 32x32 C-tiles (kv rows 0-31 / 32-63), ILP 2
            f32x16 stl = {}, sth = {};
            #pragma unroll
            for (int kk = 0; kk < 4; ++kk) {
                const int cc = kk * 2 + hi;
                bf16x8 kl = *(const bf16x8*)&Ks[cur][l31 * 64 + ((cc ^ (l31 & 7)) * 8)];
                bf16x8 kh = *(const bf16x8*)&Ks[cur][(32 + l31) * 64 + ((cc ^ (l31 & 7)) * 8)];
                stl = __builtin_amdgcn_mfma_f32_32x32x16_bf16(kl, qf[kk], stl, 0, 0, 0);
                sth = __builtin_amdgcn_mfma_f32_32x32x16_bf16(kh, qf[kk], sth, 0, 0, 0);
            }

            const int qg = q0w + l31;
            float sc0[16], sc1[16];
            float pmax = -3e38f;
            #pragma unroll
            for (int r = 0; r < 16; ++r) {
                const int koff = (r & 3) + 8 * (r >> 2) + 4 * hi;
                float a = stl[r] * 0.125f;            // 1/sqrt(64)
                float b = sth[r] * 0.125f;
                if (diag) {
                    if (kv0 + koff > qg)      a = -3e38f;
                    if (kv0 + 32 + koff > qg) b = -3e38f;
                }
                sc0[r] = a; sc1[r] = b;
                pmax = fmaxf(pmax, fmaxf(a, b));
            }
            pmax = fmaxf(pmax, __shfl_xor(pmax, 32));

            if (!__all(pmax <= m + 8.f)) {            // T13 defer-max
                const float newm = fmaxf(m, pmax);
                const float corr = __expf(m - newm);
                ll *= corr;
                #pragma unroll
                for (int r = 0; r < 16; ++r) { acc0[r] *= corr; acc1[r] *= corr; }
                m = newm;
            }
            float p0[16], p1[16], psum = 0.f;
            #pragma unroll
            for (int r = 0; r < 16; ++r) {
                p0[r] = __expf(sc0[r] - m); psum += p0[r];
                p1[r] = __expf(sc1[r] - m); psum += p1[r];
            }
            ll += psum + __shfl_xor(psum, 32);

            unsigned pw[16];
            #pragma unroll
            for (int tt = 0; tt < 8; ++tt) {
                pw[tt]     = cvt_pk_bf16(p0[2 * tt], p0[2 * tt + 1]);
                pw[8 + tt] = cvt_pk_bf16(p1[2 * tt], p1[2 * tt + 1]);
            }

            // PV: O^T += V^T . P^T over 4 k-chunks of 16
            __builtin_amdgcn_s_setprio(1);
            #pragma unroll
            for (int ck = 0; ck < 4; ++ck) {
                const int t00 = 2 * ((2 * ck) & 3) + 8 * (ck >> 1);      // h=0
                const int t10 = 2 * ((2 * ck + 1) & 3) + 8 * (ck >> 1);  // h=1
                const unsigned sw0 = hi ? pw[t10]     : pw[t00];
                const unsigned sw1 = hi ? pw[t10 + 1] : pw[t00 + 1];
                const unsigned e0i = hi ? pw[t00]     : pw[t10];
                const unsigned e1i = hi ? pw[t00 + 1] : pw[t10 + 1];
                const unsigned e0  = __shfl_xor(e0i, 32);
                const unsigned e1  = __shfl_xor(e1i, 32);
                union { unsigned u[4]; bf16x8 v; } pb;
                pb.u[0] = hi ? e0  : sw0;
                pb.u[1] = hi ? e1  : sw1;
                pb.u[2] = hi ? sw0 : e0;
                pb.u[3] = hi ? sw1 : e1;
                const int cc = ck * 2 + hi;
                bf16x8 v0 = *(const bf16x8*)&Vs[cur][l31 * 64 + ((cc ^ (l31 & 7)) * 8)];
                bf16x8 v1 = *(const bf16x8*)&Vs[cur][(32 + l31) * 64 + ((cc ^ (l31 & 7)) * 8)];
                acc0 = __builtin_amdgcn_mfma_f32_32x32x16_bf16(v0, pb.v, acc0, 0, 0, 0);
                acc1 = __builtin_amdgcn_mfma_f32_32x32x16_bf16(v1, pb.v, acc1, 0, 0, 0);
            }
            __builtin_amdgcn_s_setprio(0);
        }
        __syncthreads();                  // vmcnt(0)+barrier: next buffer ready
    }

    // epilogue: O^T row d = (reg&3)+8*(reg>>2)+4*hi (+32 for acc1), col q
    const float inv = 1.f / ll;
    const int bb = bh >> 4, hh = bh & (H - 1);
    const int q  = q0w + l31;
    unsigned short* op = ctxb + ((size_t)(bb * S + q)) * D + hh * DH;
    #pragma unroll
    for (int t = 0; t < 8; ++t) {
        const int r0 = 2 * t;
        const int d  = (r0 & 3) + 8 * (r0 >> 2) + 4 * hi;
        *(unsigned*)&op[d]      = cvt_pk_bf16(acc0[r0] * inv, acc0[r0 + 1] * inv);
        *(unsigned*)&op[32 + d] = cvt_pk_bf16(acc1[r0] * inv, acc1[r0 + 1] * inv);
    }
#undef ATTN_STAGE
}

} // namespace

extern "C" void kernel_launch(void* const* d_in, const int* in_sizes, int n_in,
                              void* d_out, int out_size, void* d_ws, size_t ws_size,
                              hipStream_t stream) {
    const float* x  = (const float*)d_in[0];
    const float* Wq = (const float*)d_in[1];
    const float* Wk = (const float*)d_in[2];
    const float* Wv = (const float*)d_in[3];
    const float* Wo = (const float*)d_in[4];
    const float* bo = (const float*)d_in[5];
    float* out = (float*)d_out;

    // ws (bf16): xb 8MB | Wt 4x2MB | Qb 8MB | Kb 8MB | Vt 8MB | ctxb 8MB = 48MB
    unsigned short* xb   = (unsigned short*)d_ws;
    unsigned short* Wt   = xb + (size_t)M * D;
    unsigned short* Qb   = Wt + (size_t)4 * D * D;
    unsigned short* Kb   = Qb + (size_t)M * D;
    unsigned short* Vtp  = Kb + (size_t)M * D;
    unsigned short* ctxb = Vtp + (size_t)M * D;

    convert_x<<<dim3((M * D) / (256 * 8)), 256, 0, stream>>>(x, xb);
    convert_w<<<dim3(D / 8, D / 64, 4), 64, 0, stream>>>(Wq, Wk, Wv, Wo, Wt);
    gemm_qkv<<<dim3(24, M / 128), 256, 0, stream>>>(xb, Wt, Qb, Kb, Vtp);
    attn_mfma32<<<dim3(512), 256, 0, stream>>>(Qb, Kb, Vtp, ctxb);
    gemm_out<<<dim3(D / 128, M / 64), 256, 0, stream>>>(
        ctxb, Wt + (size_t)3 * D * D, bo, out);
}